// Round 7
// baseline (558.473 us; speedup 1.0000x reference)
//
#include <hip/hip_runtime.h>
#include <hip/hip_bf16.h>

#define BSZ 16
#define LEN 2048
#define CH  2048
#define DIN 96
#define NST 16
#define RNK 6
#define NROW (BSZ*LEN)   // 32768
#define TCH  256
#define NCHK (LEN/TCH)   // 8
#define NPAIR (BSZ*DIN)  // 1536

typedef __attribute__((ext_vector_type(4))) float f32x4;
typedef __attribute__((ext_vector_type(8))) short bf16x8;

static __device__ __forceinline__ unsigned short f2bf(float f) {
  union { float f; unsigned u; } v; v.f = f;
  unsigned r = v.u + 0x7fff + ((v.u >> 16) & 1);   // RNE
  return (unsigned short)(r >> 16);
}

static __device__ __forceinline__ f32x4 mfma16(bf16x8 a, bf16x8 b, f32x4 c) {
  return __builtin_amdgcn_mfma_f32_16x16x32_bf16(a, b, c, 0, 0, 0);
}

// ---------------- K0: prep — W*lnw -> bf16, outW -> bf16, fold dtW@xW[:6] ----------------
__global__ void k_prep(const float* __restrict__ inW, const float* __restrict__ outW,
                       const float* __restrict__ xW, const float* __restrict__ dtW,
                       const float* __restrict__ lnw,
                       unsigned short* __restrict__ inWb, unsigned short* __restrict__ outWb,
                       float* __restrict__ M1t, float* __restrict__ xBC) {
  int i = blockIdx.x * 256 + threadIdx.x;
  if (i < DIN*CH)  inWb[i]  = f2bf(inW[i] * lnw[i & (CH-1)]);   // fold lnw into W cols
  if (i < CH*DIN)  outWb[i] = f2bf(outW[i]);
  if (i < DIN*DIN) {                 // M1t[c*96+d] = sum_r dtW[d,r]*xW[r,c]
    int c = i / DIN, d = i - c*DIN;
    float s = 0.f;
    #pragma unroll
    for (int r = 0; r < RNK; ++r) s += dtW[d*RNK + r] * xW[r*DIN + c];
    M1t[i] = s;
  }
  if (i < DIN*32) {                  // xBC[c*32+n] = xW[6+n, c]  (transposed B/C proj)
    int c = i / 32, n = i - c*32;
    xBC[i] = xW[(RNK + n)*DIN + c];
  }
}

// ---------------- K0b: pvec[d] = sum_c lnw[c]*W[d,c], qvec[d] = sum_c lnb[c]*W[d,c] ----------------
__launch_bounds__(256)
__global__ void k_prep2(const float* __restrict__ inW, const float* __restrict__ lnw,
                        const float* __restrict__ lnb,
                        float* __restrict__ pvec, float* __restrict__ qvec) {
  __shared__ float sp_[4], sq_[4];
  const int d = blockIdx.x;
  const int tid = threadIdx.x;
  const float4* w4 = (const float4*)(inW + (size_t)d*CH);
  const float4* a4 = (const float4*)lnw;
  const float4* b4 = (const float4*)lnb;
  float sp = 0.f, sq = 0.f;
  for (int j = tid; j < CH/4; j += 256) {
    float4 w = w4[j], a = a4[j], b = b4[j];
    sp += w.x*a.x + w.y*a.y + w.z*a.z + w.w*a.w;
    sq += w.x*b.x + w.y*b.y + w.z*b.z + w.w*b.w;
  }
  #pragma unroll
  for (int off = 32; off; off >>= 1) { sp += __shfl_xor(sp, off); sq += __shfl_xor(sq, off); }
  if ((tid & 63) == 0) { sp_[tid>>6] = sp; sq_[tid>>6] = sq; }
  __syncthreads();
  if (tid == 0) {
    pvec[d] = sp_[0] + sp_[1] + sp_[2] + sp_[3];
    qvec[d] = sq_[0] + sq_[1] + sq_[2] + sq_[3];
  }
}

// ---------------- K2: fused LN + in_proj, barrier-free (W frags direct from L2) ----------------
// xin[r,:] = rs*(feat[r,:] @ Wln^T) - rs*mu*p + q ; stats accumulated inline.
__launch_bounds__(256)
__global__ void k_ln_inproj(const float* __restrict__ feat,
                            const unsigned short* __restrict__ Wb,
                            const float* __restrict__ pvec, const float* __restrict__ qvec,
                            float* __restrict__ xin) {
  const int tid  = threadIdx.x;
  const int lane = tid & 63;
  const int w    = tid >> 6;
  const int r    = lane & 15;     // row within wave's 16-row tile (B-operand index)
  const int g    = lane >> 4;     // k-quadrant
  const int row  = blockIdx.x * 64 + w*16 + r;

  const float* arow = feat + (size_t)row * CH;
  const unsigned short* wrow = Wb + (size_t)r * CH + g*8;  // + ct*16*CH + t*32

  f32x4 acc[6];
  #pragma unroll
  for (int i = 0; i < 6; ++i) acc[i] = (f32x4){0.f, 0.f, 0.f, 0.f};
  float s = 0.f, q = 0.f;

  #pragma unroll 2
  for (int t = 0; t < CH/32; ++t) {        // 64 K-steps of 32
    const float* ap = arow + t*32 + g*8;
    float4 v0 = *(const float4*)ap;
    float4 v1 = *(const float4*)(ap + 4);
    s += v0.x + v0.y + v0.z + v0.w + v1.x + v1.y + v1.z + v1.w;
    q = fmaf(v0.x, v0.x, q); q = fmaf(v0.y, v0.y, q);
    q = fmaf(v0.z, v0.z, q); q = fmaf(v0.w, v0.w, q);
    q = fmaf(v1.x, v1.x, q); q = fmaf(v1.y, v1.y, q);
    q = fmaf(v1.z, v1.z, q); q = fmaf(v1.w, v1.w, q);
    union { bf16x8 v; unsigned short u[8]; } af;
    af.u[0] = f2bf(v0.x); af.u[1] = f2bf(v0.y); af.u[2] = f2bf(v0.z); af.u[3] = f2bf(v0.w);
    af.u[4] = f2bf(v1.x); af.u[5] = f2bf(v1.y); af.u[6] = f2bf(v1.z); af.u[7] = f2bf(v1.w);
    const unsigned short* wp = wrow + t*32;
    #pragma unroll
    for (int ct = 0; ct < 6; ++ct) {
      bf16x8 wf = *(const bf16x8*)(wp + (size_t)ct*16*CH);   // L2-broadcast across waves/blocks
      acc[ct] = mfma16(wf, af.v, acc[ct]);   // M-dim = W cols, N-dim = feat rows
    }
  }

  // finish row stats: lanes {r, r+16, r+32, r+48} cover disjoint k-subsets of row r
  s += __shfl_xor(s, 16); s += __shfl_xor(s, 32);
  q += __shfl_xor(q, 16); q += __shfl_xor(q, 32);
  const float mu = s * (1.f/CH);
  const float rs = rsqrtf(q*(1.f/CH) - mu*mu + 1e-5f);

  // epilogue: lane holds row, cols ct*16 + g*4 + {0..3} -> float4 stores
  float* orow = xin + (size_t)row * DIN;
  #pragma unroll
  for (int ct = 0; ct < 6; ++ct) {
    const int col = ct*16 + g*4;
    float4 pv = *(const float4*)(pvec + col);
    float4 qv = *(const float4*)(qvec + col);
    f32x4 a = acc[ct];
    float4 o;
    o.x = rs*a[0] - rs*mu*pv.x + qv.x;
    o.y = rs*a[1] - rs*mu*pv.y + qv.y;
    o.z = rs*a[2] - rs*mu*pv.z + qv.z;
    o.w = rs*a[3] - rs*mu*pv.w + qv.w;
    *(float4*)(orow + col) = o;
  }
}

// ---------------- K3: depthwise conv3 + silu + x_proj/dt_proj ----------------
// ugT/dgT are written TRANSPOSED: [b][d][t] so the scan reads t-contiguous.
#define K3_R 8
__launch_bounds__(128)
__global__ void k_conv_proj(const float* __restrict__ xin,
                            const float* __restrict__ cw, const float* __restrict__ cb,
                            const float* __restrict__ xBC, const float* __restrict__ M1t,
                            const float* __restrict__ dtb,
                            float* __restrict__ ugT, float* __restrict__ dgT,
                            float* __restrict__ Bg, float* __restrict__ Cg) {
  __shared__ float su[K3_R][DIN];
  const int b  = blockIdx.y;
  const int l0 = blockIdx.x * K3_R;
  const int t  = threadIdx.x;

  if (t < DIN) {
    float x[K3_R + 2];
    #pragma unroll
    for (int i = 0; i < K3_R + 2; ++i) {
      int li = l0 - 1 + i;
      x[i] = (li >= 0 && li < LEN) ? xin[((size_t)b*LEN + li)*DIN + t] : 0.f;
    }
    float w0 = cw[t*3], w1 = cw[t*3+1], w2 = cw[t*3+2], bb = cb[t];
    float ua[K3_R];
    #pragma unroll
    for (int r = 0; r < K3_R; ++r) {
      float c = w0*x[r] + w1*x[r+1] + w2*x[r+2] + bb;
      float uu = c / (1.f + __expf(-c));        // silu
      su[r][t] = uu;
      ua[r] = uu;
    }
    float* up = ugT + ((size_t)(b*DIN + t))*LEN + l0;
    *(float4*)(up)     = make_float4(ua[0], ua[1], ua[2], ua[3]);
    *(float4*)(up + 4) = make_float4(ua[4], ua[5], ua[6], ua[7]);
  }
  __syncthreads();
  if (t < DIN) {
    float z[K3_R];
    #pragma unroll
    for (int r = 0; r < K3_R; ++r) z[r] = dtb[t];
    for (int c = 0; c < DIN; ++c) {
      float m = M1t[c*DIN + t];                 // coalesced
      #pragma unroll
      for (int r = 0; r < K3_R; ++r) z[r] += su[r][c] * m;
    }
    float da[K3_R];
    #pragma unroll
    for (int r = 0; r < K3_R; ++r) {
      float zz = z[r];
      float sp = (zz > 20.f) ? zz : log1pf(__expf(zz));
      da[r] = 0.001f * sp;
    }
    float* dp = dgT + ((size_t)(b*DIN + t))*LEN + l0;
    *(float4*)(dp)     = make_float4(da[0], da[1], da[2], da[3]);
    *(float4*)(dp + 4) = make_float4(da[4], da[5], da[6], da[7]);
  } else if (t < DIN + 32) {
    int n = t - DIN;
    float s[K3_R];
    #pragma unroll
    for (int r = 0; r < K3_R; ++r) s[r] = 0.f;
    for (int c = 0; c < DIN; ++c) {
      float wv = xBC[c*32 + n];                 // coalesced
      #pragma unroll
      for (int r = 0; r < K3_R; ++r) s[r] += su[r][c] * wv;
    }
    #pragma unroll
    for (int r = 0; r < K3_R; ++r) {
      size_t row = (size_t)b*LEN + l0 + r;
      if (n < 16) Bg[row*NST + n]        = s[r];
      else        Cg[row*NST + (n - 16)] = s[r];
    }
  }
}

// ---------------- K4a: chunked scan pass 1 — per-chunk local state + sum(delta) ----------------
__launch_bounds__(256)
__global__ void k_scan1(const float* __restrict__ dgT, const float* __restrict__ ugT,
                        const float* __restrict__ Bg, const float* __restrict__ Alog,
                        float* __restrict__ carryS, float* __restrict__ carryD) {
  const int tid  = threadIdx.x;
  const int n    = tid & 15;
  const int pair = blockIdx.x * 16 + (tid >> 4);
  const int chunk = blockIdx.y;
  const int b = pair / DIN, d = pair - b*DIN;
  const float An = -__expf(Alog[d*NST + n]);
  const float* dp  = dgT + ((size_t)(b*DIN + d))*LEN + chunk*TCH;
  const float* up  = ugT + ((size_t)(b*DIN + d))*LEN + chunk*TCH;
  const float* bp_ = Bg + ((size_t)b*LEN + chunk*TCH)*NST + n;

  float s = 0.f, sdl = 0.f;
  #pragma unroll 2
  for (int tq = 0; tq < TCH/4; ++tq) {
    f32x4 dl4 = *(const f32x4*)(dp + tq*4);
    f32x4 uu4 = *(const f32x4*)(up + tq*4);
    #pragma unroll
    for (int j = 0; j < 4; ++j) {
      float dl = dl4[j];
      float bp = bp_[(size_t)(tq*4 + j)*NST];
      s = fmaf(__expf(dl*An), s, dl*bp*uu4[j]);
      sdl += dl;
    }
  }
  carryS[(size_t)(pair*NCHK + chunk)*16 + n] = s;
  if (n == 0) carryD[pair*NCHK + chunk] = sdl;
}

// ---------------- K4b: sequential carry combine across chunks ----------------
__launch_bounds__(256)
__global__ void k_scan2(const float* __restrict__ carryS, const float* __restrict__ carryD,
                        const float* __restrict__ Alog, float* __restrict__ xstart) {
  const int i = blockIdx.x * 256 + threadIdx.x;   // 0..24575: (pair, n)
  const int pair = i >> 4, n = i & 15;
  const int d = pair % DIN;
  const float An = -__expf(Alog[d*NST + n]);
  float x = 0.f;
  #pragma unroll
  for (int c = 0; c < NCHK; ++c) {
    xstart[(size_t)(pair*NCHK + c)*16 + n] = x;
    x = fmaf(__expf(An * carryD[pair*NCHK + c]), x, carryS[(size_t)(pair*NCHK + c)*16 + n]);
  }
}

// ---------------- K4c: chunked scan pass 2 — seeded recompute + y output ----------------
__launch_bounds__(256)
__global__ void k_scan3(const float* __restrict__ dgT, const float* __restrict__ ugT,
                        const float* __restrict__ Bg, const float* __restrict__ Cg,
                        const float* __restrict__ Alog, const float* __restrict__ Dp,
                        const float* __restrict__ xstart, unsigned short* __restrict__ yb) {
  const int tid  = threadIdx.x;
  const int n    = tid & 15;
  const int pair = blockIdx.x * 16 + (tid >> 4);
  const int chunk = blockIdx.y;
  const int b = pair / DIN, d = pair - b*DIN;
  const float An = -__expf(Alog[d*NST + n]);
  const float Dd = Dp[d];
  const float* dp  = dgT + ((size_t)(b*DIN + d))*LEN + chunk*TCH;
  const float* up  = ugT + ((size_t)(b*DIN + d))*LEN + chunk*TCH;
  const float* bp_ = Bg + ((size_t)b*LEN + chunk*TCH)*NST + n;
  const float* cp_ = Cg + ((size_t)b*LEN + chunk*TCH)*NST + n;
  unsigned short* yp = yb + ((size_t)b*LEN + chunk*TCH)*DIN + d;

  float s = xstart[(size_t)(pair*NCHK + chunk)*16 + n];
  #pragma unroll 2
  for (int tq = 0; tq < TCH/4; ++tq) {
    f32x4 dl4 = *(const f32x4*)(dp + tq*4);
    f32x4 uu4 = *(const f32x4*)(up + tq*4);
    #pragma unroll
    for (int j = 0; j < 4; ++j) {
      float dl = dl4[j];
      float bp = bp_[(size_t)(tq*4 + j)*NST];
      float cp = cp_[(size_t)(tq*4 + j)*NST];
      s = fmaf(__expf(dl*An), s, dl*bp*uu4[j]);
      float py = s * cp;
      py += __shfl_xor(py, 8);
      py += __shfl_xor(py, 4);
      py += __shfl_xor(py, 2);
      py += __shfl_xor(py, 1);
      if (n == 0) yp[(size_t)(tq*4 + j)*DIN] = f2bf(py + uu4[j]*Dd);
    }
  }
}

// ---------------- K5: out_proj, barrier-free (W direct from L2) + residual, nt stores ----------------
// 512 threads; 128x128 tile; wave = 32 rows x 64 cols (acc[4][2] = 32 VGPR).
#define K6_MR 128
#define K6_NC 128

__launch_bounds__(512)
__global__ void k_outproj(const unsigned short* __restrict__ yb,
                          const unsigned short* __restrict__ Wb,  // (2048 x 96) bf16
                          const float* __restrict__ resid,
                          float* __restrict__ out) {
  const int tid  = threadIdx.x;
  const int lane = tid & 63;
  const int ww   = tid >> 6;      // 0..7
  const int wr   = ww & 3;        // row group (32 rows each)
  const int wc   = ww >> 2;       // col group (64 cols each)
  const int r    = lane & 15;
  const int g    = lane >> 4;
  const int r0   = blockIdx.x * K6_MR;   // x = row-block: consecutive blocks share W panel
  const int c0   = blockIdx.y * K6_NC;

  f32x4 acc[4][2];
  #pragma unroll
  for (int i = 0; i < 4; ++i)
    #pragma unroll
    for (int j = 0; j < 2; ++j) acc[i][j] = (f32x4){0.f, 0.f, 0.f, 0.f};

  const unsigned short* yrow = yb + (size_t)(r0 + wr*32 + r)*DIN;
  const unsigned short* wrow = Wb + (size_t)(c0 + wc*64 + r)*DIN;
  #pragma unroll
  for (int kt = 0; kt < 3; ++kt) {     // K = 96 = 3 x 32
    const int krd = kt*32 + g*8;
    bf16x8 y0 = *(const bf16x8*)(yrow + krd);
    bf16x8 y1 = *(const bf16x8*)(yrow + 16*DIN + krd);
    #pragma unroll
    for (int ci = 0; ci < 4; ++ci) {
      bf16x8 wf = *(const bf16x8*)(wrow + (size_t)ci*16*DIN + krd);  // L2-hot
      acc[ci][0] = mfma16(wf, y0, acc[ci][0]);   // M-dim = out cols, N-dim = out rows
      acc[ci][1] = mfma16(wf, y1, acc[ci][1]);
    }
  }

  // epilogue: lane -> row (wr*32 + ri*16 + r), cols wc*64 + ci*16 + g*4: f32x4 RMW, nt store
  #pragma unroll
  for (int ci = 0; ci < 4; ++ci)
    #pragma unroll
    for (int ri = 0; ri < 2; ++ri) {
      size_t row = (size_t)(r0 + wr*32 + ri*16 + r);
      size_t col = (size_t)(c0 + wc*64 + ci*16 + g*4);
      const f32x4 rv = *(const f32x4*)(resid + row*CH + col);
      f32x4 o = acc[ci][ri] + rv;
      __builtin_nontemporal_store(o, (f32x4*)(out + row*CH + col));  // out never re-read
    }
}

extern "C" void kernel_launch(void* const* d_in, const int* in_sizes, int n_in,
                              void* d_out, int out_size, void* d_ws, size_t ws_size,
                              hipStream_t stream) {
  const float* feat = (const float*)d_in[0];
  const float* lnw  = (const float*)d_in[1];
  const float* lnb  = (const float*)d_in[2];
  const float* inW  = (const float*)d_in[3];
  const float* cw   = (const float*)d_in[4];
  const float* cb   = (const float*)d_in[5];
  const float* xW   = (const float*)d_in[6];
  const float* dtW  = (const float*)d_in[7];
  const float* dtb  = (const float*)d_in[8];
  const float* Alog = (const float*)d_in[9];
  const float* Dp   = (const float*)d_in[10];
  const float* outW = (const float*)d_in[11];
  float* out = (float*)d_out;

  char* ws = (char*)d_ws;
  size_t off = 0;
  auto alloc = [&](size_t bytes) { void* p = ws + off; off += (bytes + 255) & ~255ull; return p; };
  unsigned short* inWb  = (unsigned short*)alloc((size_t)DIN*CH*2);
  unsigned short* outWb = (unsigned short*)alloc((size_t)CH*DIN*2);
  float* M1t = (float*)alloc((size_t)DIN*DIN*4);
  float* xBC = (float*)alloc((size_t)DIN*32*4);
  float* pvec = (float*)alloc((size_t)DIN*4);
  float* qvec = (float*)alloc((size_t)DIN*4);
  float* xin = (float*)alloc((size_t)NROW*DIN*4);
  float* ugT = (float*)alloc((size_t)NROW*DIN*4);
  float* dgT = (float*)alloc((size_t)NROW*DIN*4);
  float* Bg  = (float*)alloc((size_t)NROW*NST*4);
  float* Cg  = (float*)alloc((size_t)NROW*NST*4);
  unsigned short* yb = (unsigned short*)alloc((size_t)NROW*DIN*2);
  float* carryS = (float*)alloc((size_t)NPAIR*NCHK*NST*4);
  float* carryD = (float*)alloc((size_t)NPAIR*NCHK*4);
  float* xstart = (float*)alloc((size_t)NPAIR*NCHK*NST*4);

  hipLaunchKernelGGL(k_prep, dim3((DIN*CH + 255)/256), dim3(256), 0, stream,
                     inW, outW, xW, dtW, lnw, inWb, outWb, M1t, xBC);
  hipLaunchKernelGGL(k_prep2, dim3(DIN), dim3(256), 0, stream,
                     inW, lnw, lnb, pvec, qvec);
  hipLaunchKernelGGL(k_ln_inproj, dim3(NROW/64), dim3(256), 0, stream,
                     feat, inWb, pvec, qvec, xin);
  hipLaunchKernelGGL(k_conv_proj, dim3(LEN/K3_R, BSZ), dim3(128), 0, stream,
                     xin, cw, cb, xBC, M1t, dtb, ugT, dgT, Bg, Cg);
  hipLaunchKernelGGL(k_scan1, dim3(NPAIR/16, NCHK), dim3(256), 0, stream,
                     dgT, ugT, Bg, Alog, carryS, carryD);
  hipLaunchKernelGGL(k_scan2, dim3(NPAIR*NST/256), dim3(256), 0, stream,
                     carryS, carryD, Alog, xstart);
  hipLaunchKernelGGL(k_scan3, dim3(NPAIR/16, NCHK), dim3(256), 0, stream,
                     dgT, ugT, Bg, Cg, Alog, Dp, xstart, yb);
  hipLaunchKernelGGL(k_outproj, dim3(NROW/K6_MR, CH/K6_NC), dim3(512), 0, stream,
                     yb, outWb, feat, out);
}

// Round 9
// 452.629 us; speedup vs baseline: 1.2338x; 1.2338x over previous
//
#include <hip/hip_runtime.h>
#include <hip/hip_bf16.h>

#define BSZ 16
#define LEN 2048
#define CH  2048
#define DIN 96
#define NST 16
#define RNK 6
#define NROW (BSZ*LEN)   // 32768
#define TCH  256
#define NCHK (LEN/TCH)   // 8
#define NPAIR (BSZ*DIN)  // 1536

typedef __attribute__((ext_vector_type(4))) float f32x4;
typedef __attribute__((ext_vector_type(8))) short bf16x8;

static __device__ __forceinline__ unsigned short f2bf(float f) {
  union { float f; unsigned u; } v; v.f = f;
  unsigned r = v.u + 0x7fff + ((v.u >> 16) & 1);   // RNE
  return (unsigned short)(r >> 16);
}

static __device__ __forceinline__ f32x4 mfma16(bf16x8 a, bf16x8 b, f32x4 c) {
  return __builtin_amdgcn_mfma_f32_16x16x32_bf16(a, b, c, 0, 0, 0);
}

// ---------------- K0: prep — W*lnw -> bf16, outW -> bf16, fold dtW@xW[:6] ----------------
__global__ void k_prep(const float* __restrict__ inW, const float* __restrict__ outW,
                       const float* __restrict__ xW, const float* __restrict__ dtW,
                       const float* __restrict__ lnw,
                       unsigned short* __restrict__ inWb, unsigned short* __restrict__ outWb,
                       float* __restrict__ M1t, float* __restrict__ xBC) {
  int i = blockIdx.x * 256 + threadIdx.x;
  if (i < DIN*CH)  inWb[i]  = f2bf(inW[i] * lnw[i & (CH-1)]);   // fold lnw into W cols
  if (i < CH*DIN)  outWb[i] = f2bf(outW[i]);
  if (i < DIN*DIN) {                 // M1t[c*96+d] = sum_r dtW[d,r]*xW[r,c]
    int c = i / DIN, d = i - c*DIN;
    float s = 0.f;
    #pragma unroll
    for (int r = 0; r < RNK; ++r) s += dtW[d*RNK + r] * xW[r*DIN + c];
    M1t[i] = s;
  }
  if (i < DIN*32) {                  // xBC[c*32+n] = xW[6+n, c]  (transposed B/C proj)
    int c = i / 32, n = i - c*32;
    xBC[i] = xW[(RNK + n)*DIN + c];
  }
}

// ---------------- K0b: pvec[d] = sum_c lnw[c]*W[d,c], qvec[d] = sum_c lnb[c]*W[d,c] ----------------
__launch_bounds__(256)
__global__ void k_prep2(const float* __restrict__ inW, const float* __restrict__ lnw,
                        const float* __restrict__ lnb,
                        float* __restrict__ pvec, float* __restrict__ qvec) {
  __shared__ float sp_[4], sq_[4];
  const int d = blockIdx.x;
  const int tid = threadIdx.x;
  const float4* w4 = (const float4*)(inW + (size_t)d*CH);
  const float4* a4 = (const float4*)lnw;
  const float4* b4 = (const float4*)lnb;
  float sp = 0.f, sq = 0.f;
  for (int j = tid; j < CH/4; j += 256) {
    float4 w = w4[j], a = a4[j], b = b4[j];
    sp += w.x*a.x + w.y*a.y + w.z*a.z + w.w*a.w;
    sq += w.x*b.x + w.y*b.y + w.z*b.z + w.w*b.w;
  }
  #pragma unroll
  for (int off = 32; off; off >>= 1) { sp += __shfl_xor(sp, off); sq += __shfl_xor(sq, off); }
  if ((tid & 63) == 0) { sp_[tid>>6] = sp; sq_[tid>>6] = sq; }
  __syncthreads();
  if (tid == 0) {
    pvec[d] = sp_[0] + sp_[1] + sp_[2] + sp_[3];
    qvec[d] = sq_[0] + sq_[1] + sq_[2] + sq_[3];
  }
}

// ---------------- K2: fused LN + in_proj — single-buffer W_lds, 2 barriers, reg prefetch ----------------
// xin[r,:] = rs*(feat[r,:] @ Wln^T) - rs*mu*p + q ; stats accumulated inline.
// Per chunk c: barrier(a); ds_write chunk c (regs loaded a full chunk ago); barrier(b);
// issue chunk c+1 global loads; compute chunk c. All global latency overlaps compute.
// Provably race-free: single buffer, reads and overwrites separated by two barriers.
#define K2_KC 128
#define K2_WLD 136   // 272B row stride = 17 x 16B granules (1 mod 8 -> 2-way max = free)
#define K2_NCHK (CH/K2_KC)   // 16

__launch_bounds__(256)
__global__ void k_ln_inproj(const float* __restrict__ feat,
                            const unsigned short* __restrict__ Wb,
                            const float* __restrict__ pvec, const float* __restrict__ qvec,
                            float* __restrict__ xin) {
  __shared__ unsigned short W_lds[DIN][K2_WLD];   // 26 KB

  const int tid  = threadIdx.x;
  const int lane = tid & 63;
  const int w    = tid >> 6;
  const int r    = lane & 15;     // row within wave's 16-row tile (B-operand index)
  const int g    = lane >> 4;     // k-quadrant
  const int row  = blockIdx.x * 64 + w*16 + r;

  const float* arow = feat + (size_t)row * CH;
  const int wrow = tid >> 4;              // staging row group base 0..15
  const int wcol = (tid & 15) * 8;        // staging granule col (bf16 units)
  const unsigned short* wsrc = Wb + (size_t)wrow * CH + wcol;

  f32x4 acc[6];
  #pragma unroll
  for (int i = 0; i < 6; ++i) acc[i] = (f32x4){0.f, 0.f, 0.f, 0.f};
  float s = 0.f, q = 0.f;

  // prologue: chunk 0 -> registers (feat F, weights wr_)
  float4 F[8];
  uint4 wr_[6];
  #pragma unroll
  for (int t = 0; t < 4; ++t) {
    F[2*t]   = *(const float4*)(arow + t*32 + g*8);
    F[2*t+1] = *(const float4*)(arow + t*32 + g*8 + 4);
  }
  #pragma unroll
  for (int i = 0; i < 6; ++i)
    wr_[i] = *(const uint4*)(wsrc + (size_t)(16*i)*CH);

  for (int c = 0; c < K2_NCHK; ++c) {
    __syncthreads();   // (a) all reads of previous chunk's W_lds complete
    #pragma unroll
    for (int i = 0; i < 6; ++i)
      *(uint4*)&W_lds[wrow + 16*i][wcol] = wr_[i];
    __syncthreads();   // (b) chunk c visible to all

    const bool more = (c + 1 < K2_NCHK);
    const int kcn = (c + 1) * K2_KC;
    float4 Fn[8];
    if (more) {        // issue next-chunk loads; latency hides under compute below
      #pragma unroll
      for (int t = 0; t < 4; ++t) {
        Fn[2*t]   = *(const float4*)(arow + kcn + t*32 + g*8);
        Fn[2*t+1] = *(const float4*)(arow + kcn + t*32 + g*8 + 4);
      }
      #pragma unroll
      for (int i = 0; i < 6; ++i)
        wr_[i] = *(const uint4*)(wsrc + (size_t)(16*i)*CH + kcn);
    }

    // compute chunk c from F regs + W_lds
    #pragma unroll
    for (int t = 0; t < 4; ++t) {
      float4 v0 = F[2*t], v1 = F[2*t+1];
      s += v0.x + v0.y + v0.z + v0.w + v1.x + v1.y + v1.z + v1.w;
      q = fmaf(v0.x, v0.x, q); q = fmaf(v0.y, v0.y, q);
      q = fmaf(v0.z, v0.z, q); q = fmaf(v0.w, v0.w, q);
      q = fmaf(v1.x, v1.x, q); q = fmaf(v1.y, v1.y, q);
      q = fmaf(v1.z, v1.z, q); q = fmaf(v1.w, v1.w, q);
      union { bf16x8 v; unsigned short u[8]; } af;
      af.u[0] = f2bf(v0.x); af.u[1] = f2bf(v0.y); af.u[2] = f2bf(v0.z); af.u[3] = f2bf(v0.w);
      af.u[4] = f2bf(v1.x); af.u[5] = f2bf(v1.y); af.u[6] = f2bf(v1.z); af.u[7] = f2bf(v1.w);
      const int krd = t*32 + g*8;
      #pragma unroll
      for (int ct = 0; ct < 6; ++ct) {
        bf16x8 wf = *(const bf16x8*)&W_lds[ct*16 + r][krd];
        acc[ct] = mfma16(wf, af.v, acc[ct]);   // M-dim = W cols, N-dim = feat rows
      }
    }
    if (more) {
      #pragma unroll
      for (int k = 0; k < 8; ++k) F[k] = Fn[k];
    }
  }

  // finish row stats: lanes {r, r+16, r+32, r+48} cover disjoint k-subsets of row r
  s += __shfl_xor(s, 16); s += __shfl_xor(s, 32);
  q += __shfl_xor(q, 16); q += __shfl_xor(q, 32);
  const float mu = s * (1.f/CH);
  const float rs = rsqrtf(q*(1.f/CH) - mu*mu + 1e-5f);

  // epilogue: lane holds row, cols ct*16 + g*4 + {0..3} -> float4 stores
  float* orow = xin + (size_t)row * DIN;
  #pragma unroll
  for (int ct = 0; ct < 6; ++ct) {
    const int col = ct*16 + g*4;
    float4 pv = *(const float4*)(pvec + col);
    float4 qv = *(const float4*)(qvec + col);
    f32x4 a = acc[ct];
    float4 o;
    o.x = rs*a[0] - rs*mu*pv.x + qv.x;
    o.y = rs*a[1] - rs*mu*pv.y + qv.y;
    o.z = rs*a[2] - rs*mu*pv.z + qv.z;
    o.w = rs*a[3] - rs*mu*pv.w + qv.w;
    *(float4*)(orow + col) = o;
  }
}

// ---------------- K3: depthwise conv3 + silu + x_proj/dt_proj ----------------
// ugT/dgT are written TRANSPOSED: [b][d][t] so the scan reads t-contiguous.
#define K3_R 8
__launch_bounds__(128)
__global__ void k_conv_proj(const float* __restrict__ xin,
                            const float* __restrict__ cw, const float* __restrict__ cb,
                            const float* __restrict__ xBC, const float* __restrict__ M1t,
                            const float* __restrict__ dtb,
                            float* __restrict__ ugT, float* __restrict__ dgT,
                            float* __restrict__ Bg, float* __restrict__ Cg) {
  __shared__ float su[K3_R][DIN];
  const int b  = blockIdx.y;
  const int l0 = blockIdx.x * K3_R;
  const int t  = threadIdx.x;

  if (t < DIN) {
    float x[K3_R + 2];
    #pragma unroll
    for (int i = 0; i < K3_R + 2; ++i) {
      int li = l0 - 1 + i;
      x[i] = (li >= 0 && li < LEN) ? xin[((size_t)b*LEN + li)*DIN + t] : 0.f;
    }
    float w0 = cw[t*3], w1 = cw[t*3+1], w2 = cw[t*3+2], bb = cb[t];
    float ua[K3_R];
    #pragma unroll
    for (int r = 0; r < K3_R; ++r) {
      float c = w0*x[r] + w1*x[r+1] + w2*x[r+2] + bb;
      float uu = c / (1.f + __expf(-c));        // silu
      su[r][t] = uu;
      ua[r] = uu;
    }
    float* up = ugT + ((size_t)(b*DIN + t))*LEN + l0;
    *(float4*)(up)     = make_float4(ua[0], ua[1], ua[2], ua[3]);
    *(float4*)(up + 4) = make_float4(ua[4], ua[5], ua[6], ua[7]);
  }
  __syncthreads();
  if (t < DIN) {
    float z[K3_R];
    #pragma unroll
    for (int r = 0; r < K3_R; ++r) z[r] = dtb[t];
    for (int c = 0; c < DIN; ++c) {
      float m = M1t[c*DIN + t];                 // coalesced
      #pragma unroll
      for (int r = 0; r < K3_R; ++r) z[r] += su[r][c] * m;
    }
    float da[K3_R];
    #pragma unroll
    for (int r = 0; r < K3_R; ++r) {
      float zz = z[r];
      float sp = (zz > 20.f) ? zz : log1pf(__expf(zz));
      da[r] = 0.001f * sp;
    }
    float* dp = dgT + ((size_t)(b*DIN + t))*LEN + l0;
    *(float4*)(dp)     = make_float4(da[0], da[1], da[2], da[3]);
    *(float4*)(dp + 4) = make_float4(da[4], da[5], da[6], da[7]);
  } else if (t < DIN + 32) {
    int n = t - DIN;
    float s[K3_R];
    #pragma unroll
    for (int r = 0; r < K3_R; ++r) s[r] = 0.f;
    for (int c = 0; c < DIN; ++c) {
      float wv = xBC[c*32 + n];                 // coalesced
      #pragma unroll
      for (int r = 0; r < K3_R; ++r) s[r] += su[r][c] * wv;
    }
    #pragma unroll
    for (int r = 0; r < K3_R; ++r) {
      size_t row = (size_t)b*LEN + l0 + r;
      if (n < 16) Bg[row*NST + n]        = s[r];
      else        Cg[row*NST + (n - 16)] = s[r];
    }
  }
}

// ---------------- K4a: chunked scan pass 1 — per-chunk local state + sum(delta) ----------------
__launch_bounds__(256)
__global__ void k_scan1(const float* __restrict__ dgT, const float* __restrict__ ugT,
                        const float* __restrict__ Bg, const float* __restrict__ Alog,
                        float* __restrict__ carryS, float* __restrict__ carryD) {
  const int tid  = threadIdx.x;
  const int n    = tid & 15;
  const int pair = blockIdx.x * 16 + (tid >> 4);
  const int chunk = blockIdx.y;
  const int b = pair / DIN, d = pair - b*DIN;
  const float An = -__expf(Alog[d*NST + n]);
  const float* dp  = dgT + ((size_t)(b*DIN + d))*LEN + chunk*TCH;
  const float* up  = ugT + ((size_t)(b*DIN + d))*LEN + chunk*TCH;
  const float* bp_ = Bg + ((size_t)b*LEN + chunk*TCH)*NST + n;

  float s = 0.f, sdl = 0.f;
  #pragma unroll 2
  for (int tq = 0; tq < TCH/4; ++tq) {
    f32x4 dl4 = *(const f32x4*)(dp + tq*4);
    f32x4 uu4 = *(const f32x4*)(up + tq*4);
    #pragma unroll
    for (int j = 0; j < 4; ++j) {
      float dl = dl4[j];
      float bp = bp_[(size_t)(tq*4 + j)*NST];
      s = fmaf(__expf(dl*An), s, dl*bp*uu4[j]);
      sdl += dl;
    }
  }
  carryS[(size_t)(pair*NCHK + chunk)*16 + n] = s;
  if (n == 0) carryD[pair*NCHK + chunk] = sdl;
}

// ---------------- K4b: sequential carry combine across chunks ----------------
__launch_bounds__(256)
__global__ void k_scan2(const float* __restrict__ carryS, const float* __restrict__ carryD,
                        const float* __restrict__ Alog, float* __restrict__ xstart) {
  const int i = blockIdx.x * 256 + threadIdx.x;   // 0..24575: (pair, n)
  const int pair = i >> 4, n = i & 15;
  const int d = pair % DIN;
  const float An = -__expf(Alog[d*NST + n]);
  float x = 0.f;
  #pragma unroll
  for (int c = 0; c < NCHK; ++c) {
    xstart[(size_t)(pair*NCHK + c)*16 + n] = x;
    x = fmaf(__expf(An * carryD[pair*NCHK + c]), x, carryS[(size_t)(pair*NCHK + c)*16 + n]);
  }
}

// ---------------- K4c: chunked scan pass 2 — seeded recompute + y output ----------------
__launch_bounds__(256)
__global__ void k_scan3(const float* __restrict__ dgT, const float* __restrict__ ugT,
                        const float* __restrict__ Bg, const float* __restrict__ Cg,
                        const float* __restrict__ Alog, const float* __restrict__ Dp,
                        const float* __restrict__ xstart, unsigned short* __restrict__ yb) {
  const int tid  = threadIdx.x;
  const int n    = tid & 15;
  const int pair = blockIdx.x * 16 + (tid >> 4);
  const int chunk = blockIdx.y;
  const int b = pair / DIN, d = pair - b*DIN;
  const float An = -__expf(Alog[d*NST + n]);
  const float Dd = Dp[d];
  const float* dp  = dgT + ((size_t)(b*DIN + d))*LEN + chunk*TCH;
  const float* up  = ugT + ((size_t)(b*DIN + d))*LEN + chunk*TCH;
  const float* bp_ = Bg + ((size_t)b*LEN + chunk*TCH)*NST + n;
  const float* cp_ = Cg + ((size_t)b*LEN + chunk*TCH)*NST + n;
  unsigned short* yp = yb + ((size_t)b*LEN + chunk*TCH)*DIN + d;

  float s = xstart[(size_t)(pair*NCHK + chunk)*16 + n];
  #pragma unroll 2
  for (int tq = 0; tq < TCH/4; ++tq) {
    f32x4 dl4 = *(const f32x4*)(dp + tq*4);
    f32x4 uu4 = *(const f32x4*)(up + tq*4);
    #pragma unroll
    for (int j = 0; j < 4; ++j) {
      float dl = dl4[j];
      float bp = bp_[(size_t)(tq*4 + j)*NST];
      float cp = cp_[(size_t)(tq*4 + j)*NST];
      s = fmaf(__expf(dl*An), s, dl*bp*uu4[j]);
      float py = s * cp;
      py += __shfl_xor(py, 8);
      py += __shfl_xor(py, 4);
      py += __shfl_xor(py, 2);
      py += __shfl_xor(py, 1);
      if (n == 0) yp[(size_t)(tq*4 + j)*DIN] = f2bf(py + uu4[j]*Dd);
    }
  }
}

// ---------------- K5: out_proj (bf16 MFMA, swapped operands) + residual ----------------
// Y fragments read directly from global (L2-hot, 12.6MB); only W staged in LDS. (R5-proven)
#define K6_MR 128
#define K6_NC 128
#define K6_LD 104   // 208B row stride = 13 x 16B granules (5 mod 8 -> 2-way max = free)

__launch_bounds__(256)
__global__ void k_outproj(const unsigned short* __restrict__ yb,
                          const unsigned short* __restrict__ Wb,  // (2048 x 96) bf16
                          const float* __restrict__ resid,
                          float* __restrict__ out) {
  __shared__ unsigned short W_lds[K6_NC][K6_LD];
  const int tid  = threadIdx.x;
  const int lane = tid & 63;
  const int w    = tid >> 6;
  const int r    = lane & 15;
  const int g    = lane >> 4;
  const int r0   = blockIdx.y * K6_MR;
  const int c0   = blockIdx.x * K6_NC;

  // stage W tile: 128 rows x 96 k = 12 granules/row = 1536 items = 6 x 256
  #pragma unroll
  for (int i = 0; i < 6; ++i) {
    int j = tid + 256*i;
    int row = j / 12, c8 = j - row*12;
    *(uint4*)&W_lds[row][c8*8] = *(const uint4*)(Wb + (size_t)(c0 + row)*DIN + c8*8);
  }
  __syncthreads();

  f32x4 acc[8][2];
  #pragma unroll
  for (int i = 0; i < 8; ++i)
    #pragma unroll
    for (int j = 0; j < 2; ++j) acc[i][j] = (f32x4){0.f, 0.f, 0.f, 0.f};

  const unsigned short* yrow0 = yb + (size_t)(r0 + w*32 + r)*DIN;
  #pragma unroll
  for (int kt = 0; kt < 3; ++kt) {     // K = 96 = 3 x 32
    const int krd = kt*32 + g*8;
    bf16x8 y0 = *(const bf16x8*)(yrow0 + krd);
    bf16x8 y1 = *(const bf16x8*)(yrow0 + 16*DIN + krd);
    #pragma unroll
    for (int ci = 0; ci < 8; ++ci) {
      bf16x8 wf = *(const bf16x8*)&W_lds[ci*16 + r][krd];
      acc[ci][0] = mfma16(wf, y0, acc[ci][0]);   // M-dim = out cols, N-dim = out rows
      acc[ci][1] = mfma16(wf, y1, acc[ci][1]);
    }
  }

  // epilogue: lane -> row (w*32 + ri*16 + r), cols ci*16 + g*4 + {0..3}: float4 RMW
  #pragma unroll
  for (int ci = 0; ci < 8; ++ci)
    #pragma unroll
    for (int ri = 0; ri < 2; ++ri) {
      size_t row = (size_t)(r0 + w*32 + ri*16 + r);
      size_t col = (size_t)(c0 + ci*16 + g*4);
      const float4 rv = *(const float4*)(resid + row*CH + col);
      f32x4 a = acc[ci][ri];
      float4 o = make_float4(a[0] + rv.x, a[1] + rv.y, a[2] + rv.z, a[3] + rv.w);
      *(float4*)(out + row*CH + col) = o;
    }
}

extern "C" void kernel_launch(void* const* d_in, const int* in_sizes, int n_in,
                              void* d_out, int out_size, void* d_ws, size_t ws_size,
                              hipStream_t stream) {
  const float* feat = (const float*)d_in[0];
  const float* lnw  = (const float*)d_in[1];
  const float* lnb  = (const float*)d_in[2];
  const float* inW  = (const float*)d_in[3];
  const float* cw   = (const float*)d_in[4];
  const float* cb   = (const float*)d_in[5];
  const float* xW   = (const float*)d_in[6];
  const float* dtW  = (const float*)d_in[7];
  const float* dtb  = (const float*)d_in[8];
  const float* Alog = (const float*)d_in[9];
  const float* Dp   = (const float*)d_in[10];
  const float* outW = (const float*)d_in[11];
  float* out = (float*)d_out;

  char* ws = (char*)d_ws;
  size_t off = 0;
  auto alloc = [&](size_t bytes) { void* p = ws + off; off += (bytes + 255) & ~255ull; return p; };
  unsigned short* inWb  = (unsigned short*)alloc((size_t)DIN*CH*2);
  unsigned short* outWb = (unsigned short*)alloc((size_t)CH*DIN*2);
  float* M1t = (float*)alloc((size_t)DIN*DIN*4);
  float* xBC = (float*)alloc((size_t)DIN*32*4);
  float* pvec = (float*)alloc((size_t)DIN*4);
  float* qvec = (float*)alloc((size_t)DIN*4);
  float* xin = (float*)alloc((size_t)NROW*DIN*4);
  float* ugT = (float*)alloc((size_t)NROW*DIN*4);
  float* dgT = (float*)alloc((size_t)NROW*DIN*4);
  float* Bg  = (float*)alloc((size_t)NROW*NST*4);
  float* Cg  = (float*)alloc((size_t)NROW*NST*4);
  unsigned short* yb = (unsigned short*)alloc((size_t)NROW*DIN*2);
  float* carryS = (float*)alloc((size_t)NPAIR*NCHK*NST*4);
  float* carryD = (float*)alloc((size_t)NPAIR*NCHK*4);
  float* xstart = (float*)alloc((size_t)NPAIR*NCHK*NST*4);

  hipLaunchKernelGGL(k_prep, dim3((DIN*CH + 255)/256), dim3(256), 0, stream,
                     inW, outW, xW, dtW, lnw, inWb, outWb, M1t, xBC);
  hipLaunchKernelGGL(k_prep2, dim3(DIN), dim3(256), 0, stream,
                     inW, lnw, lnb, pvec, qvec);
  hipLaunchKernelGGL(k_ln_inproj, dim3(NROW/64), dim3(256), 0, stream,
                     feat, inWb, pvec, qvec, xin);
  hipLaunchKernelGGL(k_conv_proj, dim3(LEN/K3_R, BSZ), dim3(128), 0, stream,
                     xin, cw, cb, xBC, M1t, dtb, ugT, dgT, Bg, Cg);
  hipLaunchKernelGGL(k_scan1, dim3(NPAIR/16, NCHK), dim3(256), 0, stream,
                     dgT, ugT, Bg, Alog, carryS, carryD);
  hipLaunchKernelGGL(k_scan2, dim3(NPAIR*NST/256), dim3(256), 0, stream,
                     carryS, carryD, Alog, xstart);
  hipLaunchKernelGGL(k_scan3, dim3(NPAIR/16, NCHK), dim3(256), 0, stream,
                     dgT, ugT, Bg, Cg, Alog, Dp, xstart, yb);
  hipLaunchKernelGGL(k_outproj, dim3(CH/K6_NC, NROW/K6_MR), dim3(256), 0, stream,
                     yb, outWb, feat, out);
}

// Round 10
// 425.699 us; speedup vs baseline: 1.3119x; 1.0633x over previous
//
#include <hip/hip_runtime.h>
#include <hip/hip_bf16.h>

#define BSZ 16
#define LEN 2048
#define CH  2048
#define DIN 96
#define NST 16
#define RNK 6
#define NROW (BSZ*LEN)   // 32768
#define TCH  256
#define NCHK (LEN/TCH)   // 8
#define NPAIR (BSZ*DIN)  // 1536

typedef __attribute__((ext_vector_type(4))) float f32x4;
typedef __attribute__((ext_vector_type(8))) short bf16x8;

static __device__ __forceinline__ unsigned short f2bf(float f) {
  union { float f; unsigned u; } v; v.f = f;
  unsigned r = v.u + 0x7fff + ((v.u >> 16) & 1);   // RNE
  return (unsigned short)(r >> 16);
}

static __device__ __forceinline__ f32x4 mfma16(bf16x8 a, bf16x8 b, f32x4 c) {
  return __builtin_amdgcn_mfma_f32_16x16x32_bf16(a, b, c, 0, 0, 0);
}

// ---------------- K0: prep — W*lnw -> bf16, outW -> bf16, fold dtW@xW[:6] ----------------
__global__ void k_prep(const float* __restrict__ inW, const float* __restrict__ outW,
                       const float* __restrict__ xW, const float* __restrict__ dtW,
                       const float* __restrict__ lnw,
                       unsigned short* __restrict__ inWb, unsigned short* __restrict__ outWb,
                       float* __restrict__ M1t, float* __restrict__ xBC) {
  int i = blockIdx.x * 256 + threadIdx.x;
  if (i < DIN*CH)  inWb[i]  = f2bf(inW[i] * lnw[i & (CH-1)]);   // fold lnw into W cols
  if (i < CH*DIN)  outWb[i] = f2bf(outW[i]);
  if (i < DIN*DIN) {                 // M1t[c*96+d] = sum_r dtW[d,r]*xW[r,c]
    int c = i / DIN, d = i - c*DIN;
    float s = 0.f;
    #pragma unroll
    for (int r = 0; r < RNK; ++r) s += dtW[d*RNK + r] * xW[r*DIN + c];
    M1t[i] = s;
  }
  if (i < DIN*32) {                  // xBC[c*32+n] = xW[6+n, c]  (transposed B/C proj)
    int c = i / 32, n = i - c*32;
    xBC[i] = xW[(RNK + n)*DIN + c];
  }
}

// ---------------- K0b: pvec[d] = sum_c lnw[c]*W[d,c], qvec[d] = sum_c lnb[c]*W[d,c] ----------------
__launch_bounds__(256)
__global__ void k_prep2(const float* __restrict__ inW, const float* __restrict__ lnw,
                        const float* __restrict__ lnb,
                        float* __restrict__ pvec, float* __restrict__ qvec) {
  __shared__ float sp_[4], sq_[4];
  const int d = blockIdx.x;
  const int tid = threadIdx.x;
  const float4* w4 = (const float4*)(inW + (size_t)d*CH);
  const float4* a4 = (const float4*)lnw;
  const float4* b4 = (const float4*)lnb;
  float sp = 0.f, sq = 0.f;
  for (int j = tid; j < CH/4; j += 256) {
    float4 w = w4[j], a = a4[j], b = b4[j];
    sp += w.x*a.x + w.y*a.y + w.z*a.z + w.w*a.w;
    sq += w.x*b.x + w.y*b.y + w.z*b.z + w.w*b.w;
  }
  #pragma unroll
  for (int off = 32; off; off >>= 1) { sp += __shfl_xor(sp, off); sq += __shfl_xor(sq, off); }
  if ((tid & 63) == 0) { sp_[tid>>6] = sp; sq_[tid>>6] = sq; }
  __syncthreads();
  if (tid == 0) {
    pvec[d] = sp_[0] + sp_[1] + sp_[2] + sp_[3];
    qvec[d] = sq_[0] + sq_[1] + sq_[2] + sq_[3];
  }
}

// ---------------- K2: fused LN + in_proj (R5-proven: single-buffer W_lds, 2 barriers/chunk) ----------------
// xin[r,:] = rs*(feat[r,:] @ Wln^T) - rs*mu*p + q ; stats accumulated inline.
#define K2_KC 128
#define K2_WLD 136   // 272B row stride = 17 x 16B granules (1 mod 8 -> 2-way max = free)

__launch_bounds__(256)
__global__ void k_ln_inproj(const float* __restrict__ feat,
                            const unsigned short* __restrict__ Wb,
                            const float* __restrict__ pvec, const float* __restrict__ qvec,
                            float* __restrict__ xin) {
  __shared__ unsigned short W_lds[DIN][K2_WLD];

  const int tid  = threadIdx.x;
  const int lane = tid & 63;
  const int w    = tid >> 6;
  const int r    = lane & 15;     // row within wave's 16-row tile (B-operand index)
  const int g    = lane >> 4;     // k-quadrant
  const int row  = blockIdx.x * 64 + w*16 + r;

  const float* arow = feat + (size_t)row * CH;

  f32x4 acc[6];
  #pragma unroll
  for (int i = 0; i < 6; ++i) acc[i] = (f32x4){0.f, 0.f, 0.f, 0.f};
  float s = 0.f, q = 0.f;

  for (int kc = 0; kc < CH; kc += K2_KC) {
    __syncthreads();
    // stage W chunk: 96 rows x 128 k (bf16) = 16 granules/row = 1536 items = 6 x 256
    #pragma unroll
    for (int i = 0; i < 6; ++i) {
      int j = tid + 256*i;
      int wr = j >> 4, c16 = j & 15;
      *(uint4*)&W_lds[wr][c16*8] = *(const uint4*)(Wb + (size_t)wr*CH + kc + c16*8);
    }
    __syncthreads();
    #pragma unroll
    for (int t = 0; t < 4; ++t) {
      const float* ap = arow + kc + t*32 + g*8;
      float4 v0 = *(const float4*)ap;
      float4 v1 = *(const float4*)(ap + 4);
      s += v0.x + v0.y + v0.z + v0.w + v1.x + v1.y + v1.z + v1.w;
      q = fmaf(v0.x, v0.x, q); q = fmaf(v0.y, v0.y, q);
      q = fmaf(v0.z, v0.z, q); q = fmaf(v0.w, v0.w, q);
      q = fmaf(v1.x, v1.x, q); q = fmaf(v1.y, v1.y, q);
      q = fmaf(v1.z, v1.z, q); q = fmaf(v1.w, v1.w, q);
      union { bf16x8 v; unsigned short u[8]; } af;
      af.u[0] = f2bf(v0.x); af.u[1] = f2bf(v0.y); af.u[2] = f2bf(v0.z); af.u[3] = f2bf(v0.w);
      af.u[4] = f2bf(v1.x); af.u[5] = f2bf(v1.y); af.u[6] = f2bf(v1.z); af.u[7] = f2bf(v1.w);
      const int krd = t*32 + g*8;
      #pragma unroll
      for (int ct = 0; ct < 6; ++ct) {
        bf16x8 wf = *(const bf16x8*)&W_lds[ct*16 + r][krd];
        acc[ct] = mfma16(wf, af.v, acc[ct]);   // M-dim = W cols, N-dim = feat rows
      }
    }
  }

  // finish row stats: lanes {r, r+16, r+32, r+48} cover disjoint k-subsets of row r
  s += __shfl_xor(s, 16); s += __shfl_xor(s, 32);
  q += __shfl_xor(q, 16); q += __shfl_xor(q, 32);
  const float mu = s * (1.f/CH);
  const float rs = rsqrtf(q*(1.f/CH) - mu*mu + 1e-5f);

  // epilogue: lane holds row, cols ct*16 + g*4 + {0..3} -> float4 stores
  float* orow = xin + (size_t)row * DIN;
  #pragma unroll
  for (int ct = 0; ct < 6; ++ct) {
    const int col = ct*16 + g*4;
    float4 pv = *(const float4*)(pvec + col);
    float4 qv = *(const float4*)(qvec + col);
    f32x4 a = acc[ct];
    float4 o;
    o.x = rs*a[0] - rs*mu*pv.x + qv.x;
    o.y = rs*a[1] - rs*mu*pv.y + qv.y;
    o.z = rs*a[2] - rs*mu*pv.z + qv.z;
    o.w = rs*a[3] - rs*mu*pv.w + qv.w;
    *(float4*)(orow + col) = o;
  }
}

// ---------------- K3: depthwise conv3 + silu + x_proj/dt_proj ----------------
// ugT/dgT are written TRANSPOSED: [b][d][t] so the scan reads t-contiguous.
#define K3_R 8
__launch_bounds__(128)
__global__ void k_conv_proj(const float* __restrict__ xin,
                            const float* __restrict__ cw, const float* __restrict__ cb,
                            const float* __restrict__ xBC, const float* __restrict__ M1t,
                            const float* __restrict__ dtb,
                            float* __restrict__ ugT, float* __restrict__ dgT,
                            float* __restrict__ Bg, float* __restrict__ Cg) {
  __shared__ float su[K3_R][DIN];
  const int b  = blockIdx.y;
  const int l0 = blockIdx.x * K3_R;
  const int t  = threadIdx.x;

  if (t < DIN) {
    float x[K3_R + 2];
    #pragma unroll
    for (int i = 0; i < K3_R + 2; ++i) {
      int li = l0 - 1 + i;
      x[i] = (li >= 0 && li < LEN) ? xin[((size_t)b*LEN + li)*DIN + t] : 0.f;
    }
    float w0 = cw[t*3], w1 = cw[t*3+1], w2 = cw[t*3+2], bb = cb[t];
    float ua[K3_R];
    #pragma unroll
    for (int r = 0; r < K3_R; ++r) {
      float c = w0*x[r] + w1*x[r+1] + w2*x[r+2] + bb;
      float uu = c / (1.f + __expf(-c));        // silu
      su[r][t] = uu;
      ua[r] = uu;
    }
    float* up = ugT + ((size_t)(b*DIN + t))*LEN + l0;
    *(float4*)(up)     = make_float4(ua[0], ua[1], ua[2], ua[3]);
    *(float4*)(up + 4) = make_float4(ua[4], ua[5], ua[6], ua[7]);
  }
  __syncthreads();
  if (t < DIN) {
    float z[K3_R];
    #pragma unroll
    for (int r = 0; r < K3_R; ++r) z[r] = dtb[t];
    for (int c = 0; c < DIN; ++c) {
      float m = M1t[c*DIN + t];                 // coalesced
      #pragma unroll
      for (int r = 0; r < K3_R; ++r) z[r] += su[r][c] * m;
    }
    float da[K3_R];
    #pragma unroll
    for (int r = 0; r < K3_R; ++r) {
      float zz = z[r];
      float sp = (zz > 20.f) ? zz : log1pf(__expf(zz));
      da[r] = 0.001f * sp;
    }
    float* dp = dgT + ((size_t)(b*DIN + t))*LEN + l0;
    *(float4*)(dp)     = make_float4(da[0], da[1], da[2], da[3]);
    *(float4*)(dp + 4) = make_float4(da[4], da[5], da[6], da[7]);
  } else if (t < DIN + 32) {
    int n = t - DIN;
    float s[K3_R];
    #pragma unroll
    for (int r = 0; r < K3_R; ++r) s[r] = 0.f;
    for (int c = 0; c < DIN; ++c) {
      float wv = xBC[c*32 + n];                 // coalesced
      #pragma unroll
      for (int r = 0; r < K3_R; ++r) s[r] += su[r][c] * wv;
    }
    #pragma unroll
    for (int r = 0; r < K3_R; ++r) {
      size_t row = (size_t)b*LEN + l0 + r;
      if (n < 16) Bg[row*NST + n]        = s[r];
      else        Cg[row*NST + (n - 16)] = s[r];
    }
  }
}

// ---------------- K4a: chunked scan pass 1 — per-chunk local state + sum(delta) ----------------
__launch_bounds__(256)
__global__ void k_scan1(const float* __restrict__ dgT, const float* __restrict__ ugT,
                        const float* __restrict__ Bg, const float* __restrict__ Alog,
                        float* __restrict__ carryS, float* __restrict__ carryD) {
  const int tid  = threadIdx.x;
  const int n    = tid & 15;
  const int pair = blockIdx.x * 16 + (tid >> 4);
  const int chunk = blockIdx.y;
  const int b = pair / DIN, d = pair - b*DIN;
  const float An = -__expf(Alog[d*NST + n]);
  const float* dp  = dgT + ((size_t)(b*DIN + d))*LEN + chunk*TCH;
  const float* up  = ugT + ((size_t)(b*DIN + d))*LEN + chunk*TCH;
  const float* bp_ = Bg + ((size_t)b*LEN + chunk*TCH)*NST + n;

  float s = 0.f, sdl = 0.f;
  #pragma unroll 2
  for (int tq = 0; tq < TCH/4; ++tq) {
    f32x4 dl4 = *(const f32x4*)(dp + tq*4);
    f32x4 uu4 = *(const f32x4*)(up + tq*4);
    #pragma unroll
    for (int j = 0; j < 4; ++j) {
      float dl = dl4[j];
      float bp = bp_[(size_t)(tq*4 + j)*NST];
      s = fmaf(__expf(dl*An), s, dl*bp*uu4[j]);
      sdl += dl;
    }
  }
  carryS[(size_t)(pair*NCHK + chunk)*16 + n] = s;
  if (n == 0) carryD[pair*NCHK + chunk] = sdl;
}

// ---------------- K4b: sequential carry combine across chunks ----------------
__launch_bounds__(256)
__global__ void k_scan2(const float* __restrict__ carryS, const float* __restrict__ carryD,
                        const float* __restrict__ Alog, float* __restrict__ xstart) {
  const int i = blockIdx.x * 256 + threadIdx.x;   // 0..24575: (pair, n)
  const int pair = i >> 4, n = i & 15;
  const int d = pair % DIN;
  const float An = -__expf(Alog[d*NST + n]);
  float x = 0.f;
  #pragma unroll
  for (int c = 0; c < NCHK; ++c) {
    xstart[(size_t)(pair*NCHK + c)*16 + n] = x;
    x = fmaf(__expf(An * carryD[pair*NCHK + c]), x, carryS[(size_t)(pair*NCHK + c)*16 + n]);
  }
}

// ---------------- K4c: chunked scan pass 2 — seeded recompute + y output ----------------
__launch_bounds__(256)
__global__ void k_scan3(const float* __restrict__ dgT, const float* __restrict__ ugT,
                        const float* __restrict__ Bg, const float* __restrict__ Cg,
                        const float* __restrict__ Alog, const float* __restrict__ Dp,
                        const float* __restrict__ xstart, unsigned short* __restrict__ yb) {
  const int tid  = threadIdx.x;
  const int n    = tid & 15;
  const int pair = blockIdx.x * 16 + (tid >> 4);
  const int chunk = blockIdx.y;
  const int b = pair / DIN, d = pair - b*DIN;
  const float An = -__expf(Alog[d*NST + n]);
  const float Dd = Dp[d];
  const float* dp  = dgT + ((size_t)(b*DIN + d))*LEN + chunk*TCH;
  const float* up  = ugT + ((size_t)(b*DIN + d))*LEN + chunk*TCH;
  const float* bp_ = Bg + ((size_t)b*LEN + chunk*TCH)*NST + n;
  const float* cp_ = Cg + ((size_t)b*LEN + chunk*TCH)*NST + n;
  unsigned short* yp = yb + ((size_t)b*LEN + chunk*TCH)*DIN + d;

  float s = xstart[(size_t)(pair*NCHK + chunk)*16 + n];
  #pragma unroll 2
  for (int tq = 0; tq < TCH/4; ++tq) {
    f32x4 dl4 = *(const f32x4*)(dp + tq*4);
    f32x4 uu4 = *(const f32x4*)(up + tq*4);
    #pragma unroll
    for (int j = 0; j < 4; ++j) {
      float dl = dl4[j];
      float bp = bp_[(size_t)(tq*4 + j)*NST];
      float cp = cp_[(size_t)(tq*4 + j)*NST];
      s = fmaf(__expf(dl*An), s, dl*bp*uu4[j]);
      float py = s * cp;
      py += __shfl_xor(py, 8);
      py += __shfl_xor(py, 4);
      py += __shfl_xor(py, 2);
      py += __shfl_xor(py, 1);
      if (n == 0) yp[(size_t)(tq*4 + j)*DIN] = f2bf(py + uu4[j]*Dd);
    }
  }
}

// ---------------- K5: out_proj (bf16 MFMA) + residual — 512 thr, 16 rows/wave, acc[8] ----------------
// Same 128x128 tile and math as R5-proven version; wave->row decomposition changed so
// acc = 8 f32x4 = 32 VGPR/thread (was 64) -> ~2x resident waves for the BW-bound epilogue.
#define K6_MR 128
#define K6_NC 128
#define K6_LD 104   // 208B row stride = 13 x 16B granules (5 mod 8 -> 2-way max = free)

__launch_bounds__(512)
__global__ void k_outproj(const unsigned short* __restrict__ yb,
                          const unsigned short* __restrict__ Wb,  // (2048 x 96) bf16
                          const float* __restrict__ resid,
                          float* __restrict__ out) {
  __shared__ unsigned short W_lds[K6_NC][K6_LD];
  const int tid  = threadIdx.x;
  const int lane = tid & 63;
  const int w    = tid >> 6;      // 0..7: wave's 16-row group
  const int r    = lane & 15;
  const int g    = lane >> 4;
  const int r0   = blockIdx.y * K6_MR;
  const int c0   = blockIdx.x * K6_NC;

  // stage W tile: 128 rows x 96 k = 12 granules/row = 1536 items = 3 x 512
  #pragma unroll
  for (int i = 0; i < 3; ++i) {
    int j = tid + 512*i;
    int row = j / 12, c8 = j - row*12;
    *(uint4*)&W_lds[row][c8*8] = *(const uint4*)(Wb + (size_t)(c0 + row)*DIN + c8*8);
  }
  __syncthreads();

  f32x4 acc[8];
  #pragma unroll
  for (int i = 0; i < 8; ++i) acc[i] = (f32x4){0.f, 0.f, 0.f, 0.f};

  const unsigned short* yrow = yb + (size_t)(r0 + w*16 + r)*DIN;
  #pragma unroll
  for (int kt = 0; kt < 3; ++kt) {     // K = 96 = 3 x 32
    const int krd = kt*32 + g*8;
    bf16x8 y0 = *(const bf16x8*)(yrow + krd);
    #pragma unroll
    for (int ci = 0; ci < 8; ++ci) {
      bf16x8 wf = *(const bf16x8*)&W_lds[ci*16 + r][krd];
      acc[ci] = mfma16(wf, y0, acc[ci]);   // M-dim = out cols, N-dim = out rows
    }
  }

  // epilogue: lane -> row (w*16 + r), cols ci*16 + g*4 + {0..3}: float4 RMW
  const size_t row = (size_t)(r0 + w*16 + r);
  #pragma unroll
  for (int ci = 0; ci < 8; ++ci) {
    size_t col = (size_t)(c0 + ci*16 + g*4);
    const float4 rv = *(const float4*)(resid + row*CH + col);
    f32x4 a = acc[ci];
    float4 o = make_float4(a[0] + rv.x, a[1] + rv.y, a[2] + rv.z, a[3] + rv.w);
    *(float4*)(out + row*CH + col) = o;
  }
}

extern "C" void kernel_launch(void* const* d_in, const int* in_sizes, int n_in,
                              void* d_out, int out_size, void* d_ws, size_t ws_size,
                              hipStream_t stream) {
  const float* feat = (const float*)d_in[0];
  const float* lnw  = (const float*)d_in[1];
  const float* lnb  = (const float*)d_in[2];
  const float* inW  = (const float*)d_in[3];
  const float* cw   = (const float*)d_in[4];
  const float* cb   = (const float*)d_in[5];
  const float* xW   = (const float*)d_in[6];
  const float* dtW  = (const float*)d_in[7];
  const float* dtb  = (const float*)d_in[8];
  const float* Alog = (const float*)d_in[9];
  const float* Dp   = (const float*)d_in[10];
  const float* outW = (const float*)d_in[11];
  float* out = (float*)d_out;

  char* ws = (char*)d_ws;
  size_t off = 0;
  auto alloc = [&](size_t bytes) { void* p = ws + off; off += (bytes + 255) & ~255ull; return p; };
  unsigned short* inWb  = (unsigned short*)alloc((size_t)DIN*CH*2);
  unsigned short* outWb = (unsigned short*)alloc((size_t)CH*DIN*2);
  float* M1t = (float*)alloc((size_t)DIN*DIN*4);
  float* xBC = (float*)alloc((size_t)DIN*32*4);
  float* pvec = (float*)alloc((size_t)DIN*4);
  float* qvec = (float*)alloc((size_t)DIN*4);
  float* xin = (float*)alloc((size_t)NROW*DIN*4);
  float* ugT = (float*)alloc((size_t)NROW*DIN*4);
  float* dgT = (float*)alloc((size_t)NROW*DIN*4);
  float* Bg  = (float*)alloc((size_t)NROW*NST*4);
  float* Cg  = (float*)alloc((size_t)NROW*NST*4);
  unsigned short* yb = (unsigned short*)alloc((size_t)NROW*DIN*2);
  float* carryS = (float*)alloc((size_t)NPAIR*NCHK*NST*4);
  float* carryD = (float*)alloc((size_t)NPAIR*NCHK*4);
  float* xstart = (float*)alloc((size_t)NPAIR*NCHK*NST*4);

  hipLaunchKernelGGL(k_prep, dim3((DIN*CH + 255)/256), dim3(256), 0, stream,
                     inW, outW, xW, dtW, lnw, inWb, outWb, M1t, xBC);
  hipLaunchKernelGGL(k_prep2, dim3(DIN), dim3(256), 0, stream,
                     inW, lnw, lnb, pvec, qvec);
  hipLaunchKernelGGL(k_ln_inproj, dim3(NROW/64), dim3(256), 0, stream,
                     feat, inWb, pvec, qvec, xin);
  hipLaunchKernelGGL(k_conv_proj, dim3(LEN/K3_R, BSZ), dim3(128), 0, stream,
                     xin, cw, cb, xBC, M1t, dtb, ugT, dgT, Bg, Cg);
  hipLaunchKernelGGL(k_scan1, dim3(NPAIR/16, NCHK), dim3(256), 0, stream,
                     dgT, ugT, Bg, Alog, carryS, carryD);
  hipLaunchKernelGGL(k_scan2, dim3(NPAIR*NST/256), dim3(256), 0, stream,
                     carryS, carryD, Alog, xstart);
  hipLaunchKernelGGL(k_scan3, dim3(NPAIR/16, NCHK), dim3(256), 0, stream,
                     dgT, ugT, Bg, Cg, Alog, Dp, xstart, yb);
  hipLaunchKernelGGL(k_outproj, dim3(CH/K6_NC, NROW/K6_MR), dim3(512), 0, stream,
                     yb, outWb, feat, out);
}

// Round 11
// 378.424 us; speedup vs baseline: 1.4758x; 1.1249x over previous
//
#include <hip/hip_runtime.h>
#include <hip/hip_bf16.h>

#define BSZ 16
#define LEN 2048
#define CH  2048
#define DIN 96
#define NST 16
#define RNK 6
#define NROW (BSZ*LEN)   // 32768
#define TCH  256
#define NCHK (LEN/TCH)   // 8
#define NPAIR (BSZ*DIN)  // 1536

typedef __attribute__((ext_vector_type(4))) float f32x4;
typedef __attribute__((ext_vector_type(8))) short bf16x8;

static __device__ __forceinline__ unsigned short f2bf(float f) {
  union { float f; unsigned u; } v; v.f = f;
  unsigned r = v.u + 0x7fff + ((v.u >> 16) & 1);   // RNE
  return (unsigned short)(r >> 16);
}

static __device__ __forceinline__ f32x4 mfma16(bf16x8 a, bf16x8 b, f32x4 c) {
  return __builtin_amdgcn_mfma_f32_16x16x32_bf16(a, b, c, 0, 0, 0);
}

// ---------------- K0: prep — W*lnw -> bf16, outW -> bf16, fold dtW@xW[:6] ----------------
__global__ void k_prep(const float* __restrict__ inW, const float* __restrict__ outW,
                       const float* __restrict__ xW, const float* __restrict__ dtW,
                       const float* __restrict__ lnw,
                       unsigned short* __restrict__ inWb, unsigned short* __restrict__ outWb,
                       float* __restrict__ M1t, float* __restrict__ xBC) {
  int i = blockIdx.x * 256 + threadIdx.x;
  if (i < DIN*CH)  inWb[i]  = f2bf(inW[i] * lnw[i & (CH-1)]);   // fold lnw into W cols
  if (i < CH*DIN)  outWb[i] = f2bf(outW[i]);
  if (i < DIN*DIN) {                 // M1t[c*96+d] = sum_r dtW[d,r]*xW[r,c]
    int c = i / DIN, d = i - c*DIN;
    float s = 0.f;
    #pragma unroll
    for (int r = 0; r < RNK; ++r) s += dtW[d*RNK + r] * xW[r*DIN + c];
    M1t[i] = s;
  }
  if (i < DIN*32) {                  // xBC[c*32+n] = xW[6+n, c]  (transposed B/C proj)
    int c = i / 32, n = i - c*32;
    xBC[i] = xW[(RNK + n)*DIN + c];
  }
}

// ---------------- K0b: pvec[d] = sum_c lnw[c]*W[d,c], qvec[d] = sum_c lnb[c]*W[d,c] ----------------
__launch_bounds__(256)
__global__ void k_prep2(const float* __restrict__ inW, const float* __restrict__ lnw,
                        const float* __restrict__ lnb,
                        float* __restrict__ pvec, float* __restrict__ qvec) {
  __shared__ float sp_[4], sq_[4];
  const int d = blockIdx.x;
  const int tid = threadIdx.x;
  const float4* w4 = (const float4*)(inW + (size_t)d*CH);
  const float4* a4 = (const float4*)lnw;
  const float4* b4 = (const float4*)lnb;
  float sp = 0.f, sq = 0.f;
  for (int j = tid; j < CH/4; j += 256) {
    float4 w = w4[j], a = a4[j], b = b4[j];
    sp += w.x*a.x + w.y*a.y + w.z*a.z + w.w*a.w;
    sq += w.x*b.x + w.y*b.y + w.z*b.z + w.w*b.w;
  }
  #pragma unroll
  for (int off = 32; off; off >>= 1) { sp += __shfl_xor(sp, off); sq += __shfl_xor(sq, off); }
  if ((tid & 63) == 0) { sp_[tid>>6] = sp; sq_[tid>>6] = sq; }
  __syncthreads();
  if (tid == 0) {
    pvec[d] = sp_[0] + sp_[1] + sp_[2] + sp_[3];
    qvec[d] = sq_[0] + sq_[1] + sq_[2] + sq_[3];
  }
}

// ---------------- K2: fused LN + in_proj — 512 thr, column-split waves (2x occupancy) ----------------
// xin[r,:] = rs*(feat[r,:] @ Wln^T) - rs*mu*p + q ; stats accumulated inline.
// Wave (wh,wc): rows wh*16..+15, output cols wc*48..+47 (3 MFMA tiles, acc=12 VGPR).
// Stats computed redundantly by both col-halves (identical math). W_lds single-buffer,
// 2 barriers per 128-K chunk (proven R5 structure).
#define K2_KC 128
#define K2_WLD 136   // 272B row stride = 17 x 16B granules (1 mod 8 -> 2-way max = free)

__launch_bounds__(512)
__global__ void k_ln_inproj(const float* __restrict__ feat,
                            const unsigned short* __restrict__ Wb,
                            const float* __restrict__ pvec, const float* __restrict__ qvec,
                            float* __restrict__ xin) {
  __shared__ unsigned short W_lds[DIN][K2_WLD];

  const int tid  = threadIdx.x;
  const int lane = tid & 63;
  const int w    = tid >> 6;      // 0..7
  const int wh   = w & 3;         // row group
  const int wc   = w >> 2;        // col half (0: cols 0-47, 1: cols 48-95)
  const int r    = lane & 15;
  const int g    = lane >> 4;     // k-quadrant
  const int row  = blockIdx.x * 64 + wh*16 + r;

  const float* arow = feat + (size_t)row * CH;

  f32x4 acc[3];
  #pragma unroll
  for (int i = 0; i < 3; ++i) acc[i] = (f32x4){0.f, 0.f, 0.f, 0.f};
  float s = 0.f, q = 0.f;

  for (int kc = 0; kc < CH; kc += K2_KC) {
    __syncthreads();
    // stage W chunk: 96 rows x 128 k (bf16) = 1536 granules = 3 x 512
    #pragma unroll
    for (int i = 0; i < 3; ++i) {
      int j = tid + 512*i;
      int wr = j >> 4, c16 = j & 15;
      *(uint4*)&W_lds[wr][c16*8] = *(const uint4*)(Wb + (size_t)wr*CH + kc + c16*8);
    }
    __syncthreads();
    #pragma unroll
    for (int t = 0; t < 4; ++t) {
      const float* ap = arow + kc + t*32 + g*8;
      float4 v0 = *(const float4*)ap;
      float4 v1 = *(const float4*)(ap + 4);
      s += v0.x + v0.y + v0.z + v0.w + v1.x + v1.y + v1.z + v1.w;
      q = fmaf(v0.x, v0.x, q); q = fmaf(v0.y, v0.y, q);
      q = fmaf(v0.z, v0.z, q); q = fmaf(v0.w, v0.w, q);
      q = fmaf(v1.x, v1.x, q); q = fmaf(v1.y, v1.y, q);
      q = fmaf(v1.z, v1.z, q); q = fmaf(v1.w, v1.w, q);
      union { bf16x8 v; unsigned short u[8]; } af;
      af.u[0] = f2bf(v0.x); af.u[1] = f2bf(v0.y); af.u[2] = f2bf(v0.z); af.u[3] = f2bf(v0.w);
      af.u[4] = f2bf(v1.x); af.u[5] = f2bf(v1.y); af.u[6] = f2bf(v1.z); af.u[7] = f2bf(v1.w);
      const int krd = t*32 + g*8;
      #pragma unroll
      for (int ct = 0; ct < 3; ++ct) {
        bf16x8 wf = *(const bf16x8*)&W_lds[wc*48 + ct*16 + r][krd];
        acc[ct] = mfma16(wf, af.v, acc[ct]);   // M-dim = W cols, N-dim = feat rows
      }
    }
  }

  // finish row stats: lanes {r, r+16, r+32, r+48} cover disjoint k-subsets of row r
  s += __shfl_xor(s, 16); s += __shfl_xor(s, 32);
  q += __shfl_xor(q, 16); q += __shfl_xor(q, 32);
  const float mu = s * (1.f/CH);
  const float rs = rsqrtf(q*(1.f/CH) - mu*mu + 1e-5f);

  // epilogue: lane holds row, cols wc*48 + ct*16 + g*4 + {0..3} -> float4 stores
  float* orow = xin + (size_t)row * DIN;
  #pragma unroll
  for (int ct = 0; ct < 3; ++ct) {
    const int col = wc*48 + ct*16 + g*4;
    float4 pv = *(const float4*)(pvec + col);
    float4 qv = *(const float4*)(qvec + col);
    f32x4 a = acc[ct];
    float4 o;
    o.x = rs*a[0] - rs*mu*pv.x + qv.x;
    o.y = rs*a[1] - rs*mu*pv.y + qv.y;
    o.z = rs*a[2] - rs*mu*pv.z + qv.z;
    o.w = rs*a[3] - rs*mu*pv.w + qv.w;
    *(float4*)(orow + col) = o;
  }
}

// ---------------- K3: depthwise conv3 + silu + x_proj/dt_proj ----------------
// ugT/dgT are written TRANSPOSED: [b][d][t] so the scan reads t-contiguous.
#define K3_R 8
__launch_bounds__(128)
__global__ void k_conv_proj(const float* __restrict__ xin,
                            const float* __restrict__ cw, const float* __restrict__ cb,
                            const float* __restrict__ xBC, const float* __restrict__ M1t,
                            const float* __restrict__ dtb,
                            float* __restrict__ ugT, float* __restrict__ dgT,
                            float* __restrict__ Bg, float* __restrict__ Cg) {
  __shared__ float su[K3_R][DIN];
  const int b  = blockIdx.y;
  const int l0 = blockIdx.x * K3_R;
  const int t  = threadIdx.x;

  if (t < DIN) {
    float x[K3_R + 2];
    #pragma unroll
    for (int i = 0; i < K3_R + 2; ++i) {
      int li = l0 - 1 + i;
      x[i] = (li >= 0 && li < LEN) ? xin[((size_t)b*LEN + li)*DIN + t] : 0.f;
    }
    float w0 = cw[t*3], w1 = cw[t*3+1], w2 = cw[t*3+2], bb = cb[t];
    float ua[K3_R];
    #pragma unroll
    for (int r = 0; r < K3_R; ++r) {
      float c = w0*x[r] + w1*x[r+1] + w2*x[r+2] + bb;
      float uu = c / (1.f + __expf(-c));        // silu
      su[r][t] = uu;
      ua[r] = uu;
    }
    float* up = ugT + ((size_t)(b*DIN + t))*LEN + l0;
    *(float4*)(up)     = make_float4(ua[0], ua[1], ua[2], ua[3]);
    *(float4*)(up + 4) = make_float4(ua[4], ua[5], ua[6], ua[7]);
  }
  __syncthreads();
  if (t < DIN) {
    float z[K3_R];
    #pragma unroll
    for (int r = 0; r < K3_R; ++r) z[r] = dtb[t];
    for (int c = 0; c < DIN; ++c) {
      float m = M1t[c*DIN + t];                 // coalesced
      #pragma unroll
      for (int r = 0; r < K3_R; ++r) z[r] += su[r][c] * m;
    }
    float da[K3_R];
    #pragma unroll
    for (int r = 0; r < K3_R; ++r) {
      float zz = z[r];
      float sp = (zz > 20.f) ? zz : log1pf(__expf(zz));
      da[r] = 0.001f * sp;
    }
    float* dp = dgT + ((size_t)(b*DIN + t))*LEN + l0;
    *(float4*)(dp)     = make_float4(da[0], da[1], da[2], da[3]);
    *(float4*)(dp + 4) = make_float4(da[4], da[5], da[6], da[7]);
  } else if (t < DIN + 32) {
    int n = t - DIN;
    float s[K3_R];
    #pragma unroll
    for (int r = 0; r < K3_R; ++r) s[r] = 0.f;
    for (int c = 0; c < DIN; ++c) {
      float wv = xBC[c*32 + n];                 // coalesced
      #pragma unroll
      for (int r = 0; r < K3_R; ++r) s[r] += su[r][c] * wv;
    }
    #pragma unroll
    for (int r = 0; r < K3_R; ++r) {
      size_t row = (size_t)b*LEN + l0 + r;
      if (n < 16) Bg[row*NST + n]        = s[r];
      else        Cg[row*NST + (n - 16)] = s[r];
    }
  }
}

// ---------------- K4a: chunked scan pass 1 — per-chunk local state + sum(delta) ----------------
__launch_bounds__(256)
__global__ void k_scan1(const float* __restrict__ dgT, const float* __restrict__ ugT,
                        const float* __restrict__ Bg, const float* __restrict__ Alog,
                        float* __restrict__ carryS, float* __restrict__ carryD) {
  const int tid  = threadIdx.x;
  const int n    = tid & 15;
  const int pair = blockIdx.x * 16 + (tid >> 4);
  const int chunk = blockIdx.y;
  const int b = pair / DIN, d = pair - b*DIN;
  const float An = -__expf(Alog[d*NST + n]);
  const float* dp  = dgT + ((size_t)(b*DIN + d))*LEN + chunk*TCH;
  const float* up  = ugT + ((size_t)(b*DIN + d))*LEN + chunk*TCH;
  const float* bp_ = Bg + ((size_t)b*LEN + chunk*TCH)*NST + n;

  float s = 0.f, sdl = 0.f;
  #pragma unroll 2
  for (int tq = 0; tq < TCH/4; ++tq) {
    f32x4 dl4 = *(const f32x4*)(dp + tq*4);
    f32x4 uu4 = *(const f32x4*)(up + tq*4);
    #pragma unroll
    for (int j = 0; j < 4; ++j) {
      float dl = dl4[j];
      float bp = bp_[(size_t)(tq*4 + j)*NST];
      s = fmaf(__expf(dl*An), s, dl*bp*uu4[j]);
      sdl += dl;
    }
  }
  carryS[(size_t)(pair*NCHK + chunk)*16 + n] = s;
  if (n == 0) carryD[pair*NCHK + chunk] = sdl;
}

// ---------------- K4b: sequential carry combine across chunks ----------------
__launch_bounds__(256)
__global__ void k_scan2(const float* __restrict__ carryS, const float* __restrict__ carryD,
                        const float* __restrict__ Alog, float* __restrict__ xstart) {
  const int i = blockIdx.x * 256 + threadIdx.x;   // 0..24575: (pair, n)
  const int pair = i >> 4, n = i & 15;
  const int d = pair % DIN;
  const float An = -__expf(Alog[d*NST + n]);
  float x = 0.f;
  #pragma unroll
  for (int c = 0; c < NCHK; ++c) {
    xstart[(size_t)(pair*NCHK + c)*16 + n] = x;
    x = fmaf(__expf(An * carryD[pair*NCHK + c]), x, carryS[(size_t)(pair*NCHK + c)*16 + n]);
  }
}

// ---------------- K4c: chunked scan pass 2 — seeded recompute + y output ----------------
__launch_bounds__(256)
__global__ void k_scan3(const float* __restrict__ dgT, const float* __restrict__ ugT,
                        const float* __restrict__ Bg, const float* __restrict__ Cg,
                        const float* __restrict__ Alog, const float* __restrict__ Dp,
                        const float* __restrict__ xstart, unsigned short* __restrict__ yb) {
  const int tid  = threadIdx.x;
  const int n    = tid & 15;
  const int pair = blockIdx.x * 16 + (tid >> 4);
  const int chunk = blockIdx.y;
  const int b = pair / DIN, d = pair - b*DIN;
  const float An = -__expf(Alog[d*NST + n]);
  const float Dd = Dp[d];
  const float* dp  = dgT + ((size_t)(b*DIN + d))*LEN + chunk*TCH;
  const float* up  = ugT + ((size_t)(b*DIN + d))*LEN + chunk*TCH;
  const float* bp_ = Bg + ((size_t)b*LEN + chunk*TCH)*NST + n;
  const float* cp_ = Cg + ((size_t)b*LEN + chunk*TCH)*NST + n;
  unsigned short* yp = yb + ((size_t)b*LEN + chunk*TCH)*DIN + d;

  float s = xstart[(size_t)(pair*NCHK + chunk)*16 + n];
  #pragma unroll 2
  for (int tq = 0; tq < TCH/4; ++tq) {
    f32x4 dl4 = *(const f32x4*)(dp + tq*4);
    f32x4 uu4 = *(const f32x4*)(up + tq*4);
    #pragma unroll
    for (int j = 0; j < 4; ++j) {
      float dl = dl4[j];
      float bp = bp_[(size_t)(tq*4 + j)*NST];
      float cp = cp_[(size_t)(tq*4 + j)*NST];
      s = fmaf(__expf(dl*An), s, dl*bp*uu4[j]);
      float py = s * cp;
      py += __shfl_xor(py, 8);
      py += __shfl_xor(py, 4);
      py += __shfl_xor(py, 2);
      py += __shfl_xor(py, 1);
      if (n == 0) yp[(size_t)(tq*4 + j)*DIN] = f2bf(py + uu4[j]*Dd);
    }
  }
}

// ---------------- K5: out_proj (bf16 MFMA) + residual — 512 thr, 16 rows/wave, nt stores ----------------
#define K6_MR 128
#define K6_NC 128
#define K6_LD 104   // 208B row stride = 13 x 16B granules (5 mod 8 -> 2-way max = free)

__launch_bounds__(512)
__global__ void k_outproj(const unsigned short* __restrict__ yb,
                          const unsigned short* __restrict__ Wb,  // (2048 x 96) bf16
                          const float* __restrict__ resid,
                          float* __restrict__ out) {
  __shared__ unsigned short W_lds[K6_NC][K6_LD];
  const int tid  = threadIdx.x;
  const int lane = tid & 63;
  const int w    = tid >> 6;      // 0..7: wave's 16-row group
  const int r    = lane & 15;
  const int g    = lane >> 4;
  const int r0   = blockIdx.y * K6_MR;
  const int c0   = blockIdx.x * K6_NC;

  // stage W tile: 128 rows x 96 k = 12 granules/row = 1536 items = 3 x 512
  #pragma unroll
  for (int i = 0; i < 3; ++i) {
    int j = tid + 512*i;
    int row = j / 12, c8 = j - row*12;
    *(uint4*)&W_lds[row][c8*8] = *(const uint4*)(Wb + (size_t)(c0 + row)*DIN + c8*8);
  }
  __syncthreads();

  f32x4 acc[8];
  #pragma unroll
  for (int i = 0; i < 8; ++i) acc[i] = (f32x4){0.f, 0.f, 0.f, 0.f};

  const unsigned short* yrow = yb + (size_t)(r0 + w*16 + r)*DIN;
  #pragma unroll
  for (int kt = 0; kt < 3; ++kt) {     // K = 96 = 3 x 32
    const int krd = kt*32 + g*8;
    bf16x8 y0 = *(const bf16x8*)(yrow + krd);
    #pragma unroll
    for (int ci = 0; ci < 8; ++ci) {
      bf16x8 wf = *(const bf16x8*)&W_lds[ci*16 + r][krd];
      acc[ci] = mfma16(wf, y0, acc[ci]);   // M-dim = out cols, N-dim = out rows
    }
  }

  // epilogue: lane -> row (w*16 + r), cols ci*16 + g*4 + {0..3}: f32x4 RMW, nt store
  const size_t row = (size_t)(r0 + w*16 + r);
  #pragma unroll
  for (int ci = 0; ci < 8; ++ci) {
    size_t col = (size_t)(c0 + ci*16 + g*4);
    const f32x4 rv = *(const f32x4*)(resid + row*CH + col);
    f32x4 o = acc[ci] + rv;
    __builtin_nontemporal_store(o, (f32x4*)(out + row*CH + col));  // out never re-read
  }
}

extern "C" void kernel_launch(void* const* d_in, const int* in_sizes, int n_in,
                              void* d_out, int out_size, void* d_ws, size_t ws_size,
                              hipStream_t stream) {
  const float* feat = (const float*)d_in[0];
  const float* lnw  = (const float*)d_in[1];
  const float* lnb  = (const float*)d_in[2];
  const float* inW  = (const float*)d_in[3];
  const float* cw   = (const float*)d_in[4];
  const float* cb   = (const float*)d_in[5];
  const float* xW   = (const float*)d_in[6];
  const float* dtW  = (const float*)d_in[7];
  const float* dtb  = (const float*)d_in[8];
  const float* Alog = (const float*)d_in[9];
  const float* Dp   = (const float*)d_in[10];
  const float* outW = (const float*)d_in[11];
  float* out = (float*)d_out;

  char* ws = (char*)d_ws;
  size_t off = 0;
  auto alloc = [&](size_t bytes) { void* p = ws + off; off += (bytes + 255) & ~255ull; return p; };
  unsigned short* inWb  = (unsigned short*)alloc((size_t)DIN*CH*2);
  unsigned short* outWb = (unsigned short*)alloc((size_t)CH*DIN*2);
  float* M1t = (float*)alloc((size_t)DIN*DIN*4);
  float* xBC = (float*)alloc((size_t)DIN*32*4);
  float* pvec = (float*)alloc((size_t)DIN*4);
  float* qvec = (float*)alloc((size_t)DIN*4);
  float* xin = (float*)alloc((size_t)NROW*DIN*4);
  float* ugT = (float*)alloc((size_t)NROW*DIN*4);
  float* dgT = (float*)alloc((size_t)NROW*DIN*4);
  float* Bg  = (float*)alloc((size_t)NROW*NST*4);
  float* Cg  = (float*)alloc((size_t)NROW*NST*4);
  unsigned short* yb = (unsigned short*)alloc((size_t)NROW*DIN*2);
  float* carryS = (float*)alloc((size_t)NPAIR*NCHK*NST*4);
  float* carryD = (float*)alloc((size_t)NPAIR*NCHK*4);
  float* xstart = (float*)alloc((size_t)NPAIR*NCHK*NST*4);

  hipLaunchKernelGGL(k_prep, dim3((DIN*CH + 255)/256), dim3(256), 0, stream,
                     inW, outW, xW, dtW, lnw, inWb, outWb, M1t, xBC);
  hipLaunchKernelGGL(k_prep2, dim3(DIN), dim3(256), 0, stream,
                     inW, lnw, lnb, pvec, qvec);
  hipLaunchKernelGGL(k_ln_inproj, dim3(NROW/64), dim3(512), 0, stream,
                     feat, inWb, pvec, qvec, xin);
  hipLaunchKernelGGL(k_conv_proj, dim3(LEN/K3_R, BSZ), dim3(128), 0, stream,
                     xin, cw, cb, xBC, M1t, dtb, ugT, dgT, Bg, Cg);
  hipLaunchKernelGGL(k_scan1, dim3(NPAIR/16, NCHK), dim3(256), 0, stream,
                     dgT, ugT, Bg, Alog, carryS, carryD);
  hipLaunchKernelGGL(k_scan2, dim3(NPAIR*NST/256), dim3(256), 0, stream,
                     carryS, carryD, Alog, xstart);
  hipLaunchKernelGGL(k_scan3, dim3(NPAIR/16, NCHK), dim3(256), 0, stream,
                     dgT, ugT, Bg, Cg, Alog, Dp, xstart, yb);
  hipLaunchKernelGGL(k_outproj, dim3(CH/K6_NC, NROW/K6_MR), dim3(512), 0, stream,
                     yb, outWb, feat, out);
}

// Round 12
// 357.807 us; speedup vs baseline: 1.5608x; 1.0576x over previous
//
#include <hip/hip_runtime.h>
#include <hip/hip_bf16.h>

#define BSZ 16
#define LEN 2048
#define CH  2048
#define DIN 96
#define NST 16
#define RNK 6
#define NROW (BSZ*LEN)   // 32768
#define TCH  128
#define NCHK (LEN/TCH)   // 16
#define NPAIR (BSZ*DIN)  // 1536

typedef __attribute__((ext_vector_type(4))) float f32x4;
typedef __attribute__((ext_vector_type(8))) short bf16x8;

static __device__ __forceinline__ unsigned short f2bf(float f) {
  union { float f; unsigned u; } v; v.f = f;
  unsigned r = v.u + 0x7fff + ((v.u >> 16) & 1);   // RNE
  return (unsigned short)(r >> 16);
}

static __device__ __forceinline__ f32x4 mfma16(bf16x8 a, bf16x8 b, f32x4 c) {
  return __builtin_amdgcn_mfma_f32_16x16x32_bf16(a, b, c, 0, 0, 0);
}

// ---------------- K0: prep — W*lnw -> bf16, outW -> bf16, fold dtW@xW[:6] ----------------
__global__ void k_prep(const float* __restrict__ inW, const float* __restrict__ outW,
                       const float* __restrict__ xW, const float* __restrict__ dtW,
                       const float* __restrict__ lnw,
                       unsigned short* __restrict__ inWb, unsigned short* __restrict__ outWb,
                       float* __restrict__ M1t, float* __restrict__ xBC) {
  int i = blockIdx.x * 256 + threadIdx.x;
  if (i < DIN*CH)  inWb[i]  = f2bf(inW[i] * lnw[i & (CH-1)]);   // fold lnw into W cols
  if (i < CH*DIN)  outWb[i] = f2bf(outW[i]);
  if (i < DIN*DIN) {                 // M1t[c*96+d] = sum_r dtW[d,r]*xW[r,c]
    int c = i / DIN, d = i - c*DIN;
    float s = 0.f;
    #pragma unroll
    for (int r = 0; r < RNK; ++r) s += dtW[d*RNK + r] * xW[r*DIN + c];
    M1t[i] = s;
  }
  if (i < DIN*32) {                  // xBC[c*32+n] = xW[6+n, c]  (transposed B/C proj)
    int c = i / 32, n = i - c*32;
    xBC[i] = xW[(RNK + n)*DIN + c];
  }
}

// ---------------- K0b: pvec[d] = sum_c lnw[c]*W[d,c], qvec[d] = sum_c lnb[c]*W[d,c] ----------------
__launch_bounds__(256)
__global__ void k_prep2(const float* __restrict__ inW, const float* __restrict__ lnw,
                        const float* __restrict__ lnb,
                        float* __restrict__ pvec, float* __restrict__ qvec) {
  __shared__ float sp_[4], sq_[4];
  const int d = blockIdx.x;
  const int tid = threadIdx.x;
  const float4* w4 = (const float4*)(inW + (size_t)d*CH);
  const float4* a4 = (const float4*)lnw;
  const float4* b4 = (const float4*)lnb;
  float sp = 0.f, sq = 0.f;
  for (int j = tid; j < CH/4; j += 256) {
    float4 w = w4[j], a = a4[j], b = b4[j];
    sp += w.x*a.x + w.y*a.y + w.z*a.z + w.w*a.w;
    sq += w.x*b.x + w.y*b.y + w.z*b.z + w.w*b.w;
  }
  #pragma unroll
  for (int off = 32; off; off >>= 1) { sp += __shfl_xor(sp, off); sq += __shfl_xor(sq, off); }
  if ((tid & 63) == 0) { sp_[tid>>6] = sp; sq_[tid>>6] = sq; }
  __syncthreads();
  if (tid == 0) {
    pvec[d] = sp_[0] + sp_[1] + sp_[2] + sp_[3];
    qvec[d] = sq_[0] + sq_[1] + sq_[2] + sq_[3];
  }
}

// ---------------- K2: fused LN + in_proj — 512 thr, column-split waves, nt feat loads ----------------
#define K2_KC 128
#define K2_WLD 136   // 272B row stride = 17 x 16B granules (1 mod 8 -> 2-way max = free)

__launch_bounds__(512)
__global__ void k_ln_inproj(const float* __restrict__ feat,
                            const unsigned short* __restrict__ Wb,
                            const float* __restrict__ pvec, const float* __restrict__ qvec,
                            float* __restrict__ xin) {
  __shared__ unsigned short W_lds[DIN][K2_WLD];

  const int tid  = threadIdx.x;
  const int lane = tid & 63;
  const int w    = tid >> 6;      // 0..7
  const int wh   = w & 3;         // row group
  const int wc   = w >> 2;        // col half (0: cols 0-47, 1: cols 48-95)
  const int r    = lane & 15;
  const int g    = lane >> 4;     // k-quadrant
  const int row  = blockIdx.x * 64 + wh*16 + r;

  const float* arow = feat + (size_t)row * CH;

  f32x4 acc[3];
  #pragma unroll
  for (int i = 0; i < 3; ++i) acc[i] = (f32x4){0.f, 0.f, 0.f, 0.f};
  float s = 0.f, q = 0.f;

  for (int kc = 0; kc < CH; kc += K2_KC) {
    __syncthreads();
    // stage W chunk: 96 rows x 128 k (bf16) = 1536 granules = 3 x 512
    #pragma unroll
    for (int i = 0; i < 3; ++i) {
      int j = tid + 512*i;
      int wr = j >> 4, c16 = j & 15;
      *(uint4*)&W_lds[wr][c16*8] = *(const uint4*)(Wb + (size_t)wr*CH + kc + c16*8);
    }
    __syncthreads();
    #pragma unroll
    for (int t = 0; t < 4; ++t) {
      const f32x4* ap = (const f32x4*)(arow + kc + t*32 + g*8);
      f32x4 v0 = __builtin_nontemporal_load(ap);       // feat: streamed once, keep out of L2
      f32x4 v1 = __builtin_nontemporal_load(ap + 1);
      s += v0[0] + v0[1] + v0[2] + v0[3] + v1[0] + v1[1] + v1[2] + v1[3];
      #pragma unroll
      for (int k = 0; k < 4; ++k) { q = fmaf(v0[k], v0[k], q); q = fmaf(v1[k], v1[k], q); }
      union { bf16x8 v; unsigned short u[8]; } af;
      #pragma unroll
      for (int k = 0; k < 4; ++k) { af.u[k] = f2bf(v0[k]); af.u[4+k] = f2bf(v1[k]); }
      const int krd = t*32 + g*8;
      #pragma unroll
      for (int ct = 0; ct < 3; ++ct) {
        bf16x8 wf = *(const bf16x8*)&W_lds[wc*48 + ct*16 + r][krd];
        acc[ct] = mfma16(wf, af.v, acc[ct]);   // M-dim = W cols, N-dim = feat rows
      }
    }
  }

  // finish row stats: lanes {r, r+16, r+32, r+48} cover disjoint k-subsets of row r
  s += __shfl_xor(s, 16); s += __shfl_xor(s, 32);
  q += __shfl_xor(q, 16); q += __shfl_xor(q, 32);
  const float mu = s * (1.f/CH);
  const float rs = rsqrtf(q*(1.f/CH) - mu*mu + 1e-5f);

  // epilogue: lane holds row, cols wc*48 + ct*16 + g*4 + {0..3} -> float4 stores
  float* orow = xin + (size_t)row * DIN;
  #pragma unroll
  for (int ct = 0; ct < 3; ++ct) {
    const int col = wc*48 + ct*16 + g*4;
    float4 pv = *(const float4*)(pvec + col);
    float4 qv = *(const float4*)(qvec + col);
    f32x4 a = acc[ct];
    float4 o;
    o.x = rs*a[0] - rs*mu*pv.x + qv.x;
    o.y = rs*a[1] - rs*mu*pv.y + qv.y;
    o.z = rs*a[2] - rs*mu*pv.z + qv.z;
    o.w = rs*a[3] - rs*mu*pv.w + qv.w;
    *(float4*)(orow + col) = o;
  }
}

// ---------------- K3: depthwise conv3 + silu + x_proj/dt_proj ----------------
// ugT/dgT are written TRANSPOSED: [b][d][t] so the scan reads t-contiguous.
#define K3_R 8
__launch_bounds__(128)
__global__ void k_conv_proj(const float* __restrict__ xin,
                            const float* __restrict__ cw, const float* __restrict__ cb,
                            const float* __restrict__ xBC, const float* __restrict__ M1t,
                            const float* __restrict__ dtb,
                            float* __restrict__ ugT, float* __restrict__ dgT,
                            float* __restrict__ Bg, float* __restrict__ Cg) {
  __shared__ float su[K3_R][DIN];
  const int b  = blockIdx.y;
  const int l0 = blockIdx.x * K3_R;
  const int t  = threadIdx.x;

  if (t < DIN) {
    float x[K3_R + 2];
    #pragma unroll
    for (int i = 0; i < K3_R + 2; ++i) {
      int li = l0 - 1 + i;
      x[i] = (li >= 0 && li < LEN) ? xin[((size_t)b*LEN + li)*DIN + t] : 0.f;
    }
    float w0 = cw[t*3], w1 = cw[t*3+1], w2 = cw[t*3+2], bb = cb[t];
    float ua[K3_R];
    #pragma unroll
    for (int r = 0; r < K3_R; ++r) {
      float c = w0*x[r] + w1*x[r+1] + w2*x[r+2] + bb;
      float uu = c / (1.f + __expf(-c));        // silu
      su[r][t] = uu;
      ua[r] = uu;
    }
    float* up = ugT + ((size_t)(b*DIN + t))*LEN + l0;
    *(float4*)(up)     = make_float4(ua[0], ua[1], ua[2], ua[3]);
    *(float4*)(up + 4) = make_float4(ua[4], ua[5], ua[6], ua[7]);
  }
  __syncthreads();
  if (t < DIN) {
    float z[K3_R];
    #pragma unroll
    for (int r = 0; r < K3_R; ++r) z[r] = dtb[t];
    for (int c = 0; c < DIN; ++c) {
      float m = M1t[c*DIN + t];                 // coalesced
      #pragma unroll
      for (int r = 0; r < K3_R; ++r) z[r] += su[r][c] * m;
    }
    float da[K3_R];
    #pragma unroll
    for (int r = 0; r < K3_R; ++r) {
      float zz = z[r];
      float sp = (zz > 20.f) ? zz : log1pf(__expf(zz));
      da[r] = 0.001f * sp;
    }
    float* dp = dgT + ((size_t)(b*DIN + t))*LEN + l0;
    *(float4*)(dp)     = make_float4(da[0], da[1], da[2], da[3]);
    *(float4*)(dp + 4) = make_float4(da[4], da[5], da[6], da[7]);
  } else if (t < DIN + 32) {
    int n = t - DIN;
    float s[K3_R];
    #pragma unroll
    for (int r = 0; r < K3_R; ++r) s[r] = 0.f;
    for (int c = 0; c < DIN; ++c) {
      float wv = xBC[c*32 + n];                 // coalesced
      #pragma unroll
      for (int r = 0; r < K3_R; ++r) s[r] += su[r][c] * wv;
    }
    #pragma unroll
    for (int r = 0; r < K3_R; ++r) {
      size_t row = (size_t)b*LEN + l0 + r;
      if (n < 16) Bg[row*NST + n]        = s[r];
      else        Cg[row*NST + (n - 16)] = s[r];
    }
  }
}

// ---------------- K4a: chunked scan pass 1 — 4 states/lane, f32x4 B loads ----------------
// lane quad (nq=tid&3) holds n = nq*4..+3 of pair (tid>>2); 64 pairs/block; grid (24, 16)
__launch_bounds__(256)
__global__ void k_scan1(const float* __restrict__ dgT, const float* __restrict__ ugT,
                        const float* __restrict__ Bg, const float* __restrict__ Alog,
                        float* __restrict__ carryS, float* __restrict__ carryD) {
  const int tid  = threadIdx.x;
  const int nq   = tid & 3;
  const int pair = blockIdx.x * 64 + (tid >> 2);
  const int chunk = blockIdx.y;
  const int b = pair / DIN, d = pair - b*DIN;
  f32x4 Al = *(const f32x4*)(Alog + d*NST + nq*4);
  f32x4 An4;
  #pragma unroll
  for (int k = 0; k < 4; ++k) An4[k] = -__expf(Al[k]);
  const float* dp  = dgT + ((size_t)(b*DIN + d))*LEN + chunk*TCH;
  const float* up  = ugT + ((size_t)(b*DIN + d))*LEN + chunk*TCH;
  const float* bp_ = Bg + ((size_t)b*LEN + chunk*TCH)*NST + nq*4;

  f32x4 s4 = (f32x4){0.f, 0.f, 0.f, 0.f};
  float sdl = 0.f;
  #pragma unroll 2
  for (int tq = 0; tq < TCH/4; ++tq) {
    f32x4 dl4 = *(const f32x4*)(dp + tq*4);
    f32x4 uu4 = *(const f32x4*)(up + tq*4);
    #pragma unroll
    for (int j = 0; j < 4; ++j) {
      float dl = dl4[j];
      f32x4 bp4 = *(const f32x4*)(bp_ + (size_t)(tq*4 + j)*NST);
      f32x4 dA;
      #pragma unroll
      for (int k = 0; k < 4; ++k) dA[k] = __expf(dl*An4[k]);
      float du = dl * uu4[j];
      s4 = dA*s4 + du*bp4;
      sdl += dl;
    }
  }
  *(f32x4*)(carryS + (size_t)(pair*NCHK + chunk)*16 + nq*4) = s4;
  if (nq == 0) carryD[pair*NCHK + chunk] = sdl;
}

// ---------------- K4b: sequential carry combine across chunks ----------------
__launch_bounds__(256)
__global__ void k_scan2(const float* __restrict__ carryS, const float* __restrict__ carryD,
                        const float* __restrict__ Alog, float* __restrict__ xstart) {
  const int i = blockIdx.x * 256 + threadIdx.x;   // 0..24575: (pair, n)
  const int pair = i >> 4, n = i & 15;
  const int d = pair % DIN;
  const float An = -__expf(Alog[d*NST + n]);
  float x = 0.f;
  #pragma unroll
  for (int c = 0; c < NCHK; ++c) {
    xstart[(size_t)(pair*NCHK + c)*16 + n] = x;
    x = fmaf(__expf(An * carryD[pair*NCHK + c]), x, carryS[(size_t)(pair*NCHK + c)*16 + n]);
  }
}

// ---------------- K4c: chunked scan pass 2 — 4 states/lane, dot4 + 2-shfl reduce ----------------
__launch_bounds__(256)
__global__ void k_scan3(const float* __restrict__ dgT, const float* __restrict__ ugT,
                        const float* __restrict__ Bg, const float* __restrict__ Cg,
                        const float* __restrict__ Alog, const float* __restrict__ Dp,
                        const float* __restrict__ xstart, unsigned short* __restrict__ yb) {
  const int tid  = threadIdx.x;
  const int nq   = tid & 3;
  const int pair = blockIdx.x * 64 + (tid >> 2);
  const int chunk = blockIdx.y;
  const int b = pair / DIN, d = pair - b*DIN;
  f32x4 Al = *(const f32x4*)(Alog + d*NST + nq*4);
  f32x4 An4;
  #pragma unroll
  for (int k = 0; k < 4; ++k) An4[k] = -__expf(Al[k]);
  const float Dd = Dp[d];
  const float* dp  = dgT + ((size_t)(b*DIN + d))*LEN + chunk*TCH;
  const float* up  = ugT + ((size_t)(b*DIN + d))*LEN + chunk*TCH;
  const float* bp_ = Bg + ((size_t)b*LEN + chunk*TCH)*NST + nq*4;
  const float* cp_ = Cg + ((size_t)b*LEN + chunk*TCH)*NST + nq*4;
  unsigned short* yp = yb + ((size_t)b*LEN + chunk*TCH)*DIN + d;

  f32x4 s4 = *(const f32x4*)(xstart + (size_t)(pair*NCHK + chunk)*16 + nq*4);
  #pragma unroll 2
  for (int tq = 0; tq < TCH/4; ++tq) {
    f32x4 dl4 = *(const f32x4*)(dp + tq*4);
    f32x4 uu4 = *(const f32x4*)(up + tq*4);
    #pragma unroll
    for (int j = 0; j < 4; ++j) {
      float dl = dl4[j];
      f32x4 bp4 = *(const f32x4*)(bp_ + (size_t)(tq*4 + j)*NST);
      f32x4 cp4 = *(const f32x4*)(cp_ + (size_t)(tq*4 + j)*NST);
      f32x4 dA;
      #pragma unroll
      for (int k = 0; k < 4; ++k) dA[k] = __expf(dl*An4[k]);
      float du = dl * uu4[j];
      s4 = dA*s4 + du*bp4;
      f32x4 pv = s4 * cp4;
      float py = (pv[0] + pv[1]) + (pv[2] + pv[3]);
      py += __shfl_xor(py, 1);
      py += __shfl_xor(py, 2);
      if (nq == 0) yp[(size_t)(tq*4 + j)*DIN] = f2bf(py + uu4[j]*Dd);
    }
  }
}

// ---------------- K5: out_proj (bf16 MFMA) + residual — 512 thr, nt load/store epilogue ----------------
#define K6_MR 128
#define K6_NC 128
#define K6_LD 104   // 208B row stride = 13 x 16B granules (5 mod 8 -> 2-way max = free)

__launch_bounds__(512)
__global__ void k_outproj(const unsigned short* __restrict__ yb,
                          const unsigned short* __restrict__ Wb,  // (2048 x 96) bf16
                          const float* __restrict__ resid,
                          float* __restrict__ out) {
  __shared__ unsigned short W_lds[K6_NC][K6_LD];
  const int tid  = threadIdx.x;
  const int lane = tid & 63;
  const int w    = tid >> 6;      // 0..7: wave's 16-row group
  const int r    = lane & 15;
  const int g    = lane >> 4;
  const int r0   = blockIdx.y * K6_MR;
  const int c0   = blockIdx.x * K6_NC;

  // stage W tile: 128 rows x 96 k = 12 granules/row = 1536 items = 3 x 512
  #pragma unroll
  for (int i = 0; i < 3; ++i) {
    int j = tid + 512*i;
    int row = j / 12, c8 = j - row*12;
    *(uint4*)&W_lds[row][c8*8] = *(const uint4*)(Wb + (size_t)(c0 + row)*DIN + c8*8);
  }
  __syncthreads();

  f32x4 acc[8];
  #pragma unroll
  for (int i = 0; i < 8; ++i) acc[i] = (f32x4){0.f, 0.f, 0.f, 0.f};

  const unsigned short* yrow = yb + (size_t)(r0 + w*16 + r)*DIN;
  #pragma unroll
  for (int kt = 0; kt < 3; ++kt) {     // K = 96 = 3 x 32
    const int krd = kt*32 + g*8;
    bf16x8 y0 = *(const bf16x8*)(yrow + krd);
    #pragma unroll
    for (int ci = 0; ci < 8; ++ci) {
      bf16x8 wf = *(const bf16x8*)&W_lds[ci*16 + r][krd];
      acc[ci] = mfma16(wf, y0, acc[ci]);   // M-dim = out cols, N-dim = out rows
    }
  }

  // epilogue: lane -> row (w*16 + r), cols ci*16 + g*4 + {0..3}: nt f32x4 RMW
  const size_t row = (size_t)(r0 + w*16 + r);
  #pragma unroll
  for (int ci = 0; ci < 8; ++ci) {
    size_t col = (size_t)(c0 + ci*16 + g*4);
    const f32x4 rv = __builtin_nontemporal_load((const f32x4*)(resid + row*CH + col));
    f32x4 o = acc[ci] + rv;
    __builtin_nontemporal_store(o, (f32x4*)(out + row*CH + col));  // out never re-read
  }
}

extern "C" void kernel_launch(void* const* d_in, const int* in_sizes, int n_in,
                              void* d_out, int out_size, void* d_ws, size_t ws_size,
                              hipStream_t stream) {
  const float* feat = (const float*)d_in[0];
  const float* lnw  = (const float*)d_in[1];
  const float* lnb  = (const float*)d_in[2];
  const float* inW  = (const float*)d_in[3];
  const float* cw   = (const float*)d_in[4];
  const float* cb   = (const float*)d_in[5];
  const float* xW   = (const float*)d_in[6];
  const float* dtW  = (const float*)d_in[7];
  const float* dtb  = (const float*)d_in[8];
  const float* Alog = (const float*)d_in[9];
  const float* Dp   = (const float*)d_in[10];
  const float* outW = (const float*)d_in[11];
  float* out = (float*)d_out;

  char* ws = (char*)d_ws;
  size_t off = 0;
  auto alloc = [&](size_t bytes) { void* p = ws + off; off += (bytes + 255) & ~255ull; return p; };
  unsigned short* inWb  = (unsigned short*)alloc((size_t)DIN*CH*2);
  unsigned short* outWb = (unsigned short*)alloc((size_t)CH*DIN*2);
  float* M1t = (float*)alloc((size_t)DIN*DIN*4);
  float* xBC = (float*)alloc((size_t)DIN*32*4);
  float* pvec = (float*)alloc((size_t)DIN*4);
  float* qvec = (float*)alloc((size_t)DIN*4);
  float* xin = (float*)alloc((size_t)NROW*DIN*4);
  float* ugT = (float*)alloc((size_t)NROW*DIN*4);
  float* dgT = (float*)alloc((size_t)NROW*DIN*4);
  float* Bg  = (float*)alloc((size_t)NROW*NST*4);
  float* Cg  = (float*)alloc((size_t)NROW*NST*4);
  unsigned short* yb = (unsigned short*)alloc((size_t)NROW*DIN*2);
  float* carryS = (float*)alloc((size_t)NPAIR*NCHK*NST*4);
  float* carryD = (float*)alloc((size_t)NPAIR*NCHK*4);
  float* xstart = (float*)alloc((size_t)NPAIR*NCHK*NST*4);

  hipLaunchKernelGGL(k_prep, dim3((DIN*CH + 255)/256), dim3(256), 0, stream,
                     inW, outW, xW, dtW, lnw, inWb, outWb, M1t, xBC);
  hipLaunchKernelGGL(k_prep2, dim3(DIN), dim3(256), 0, stream,
                     inW, lnw, lnb, pvec, qvec);
  hipLaunchKernelGGL(k_ln_inproj, dim3(NROW/64), dim3(512), 0, stream,
                     feat, inWb, pvec, qvec, xin);
  hipLaunchKernelGGL(k_conv_proj, dim3(LEN/K3_R, BSZ), dim3(128), 0, stream,
                     xin, cw, cb, xBC, M1t, dtb, ugT, dgT, Bg, Cg);
  hipLaunchKernelGGL(k_scan1, dim3(NPAIR/64, NCHK), dim3(256), 0, stream,
                     dgT, ugT, Bg, Alog, carryS, carryD);
  hipLaunchKernelGGL(k_scan2, dim3(NPAIR*NST/256), dim3(256), 0, stream,
                     carryS, carryD, Alog, xstart);
  hipLaunchKernelGGL(k_scan3, dim3(NPAIR/64, NCHK), dim3(256), 0, stream,
                     dgT, ugT, Bg, Cg, Alog, Dp, xstart, yb);
  hipLaunchKernelGGL(k_outproj, dim3(CH/K6_NC, NROW/K6_MR), dim3(512), 0, stream,
                     yb, outWb, feat, out);
}

// Round 13
// 346.288 us; speedup vs baseline: 1.6127x; 1.0333x over previous
//
#include <hip/hip_runtime.h>
#include <hip/hip_bf16.h>

#define BSZ 16
#define LEN 2048
#define CH  2048
#define DIN 96
#define NST 16
#define RNK 6
#define NROW (BSZ*LEN)   // 32768
#define TCH  64
#define NCHK (LEN/TCH)   // 32
#define NPAIR (BSZ*DIN)  // 1536

typedef __attribute__((ext_vector_type(4))) float f32x4;
typedef __attribute__((ext_vector_type(4))) unsigned u32x4;
typedef __attribute__((ext_vector_type(8))) short bf16x8;

static __device__ __forceinline__ unsigned short f2bf(float f) {
  union { float f; unsigned u; } v; v.f = f;
  unsigned r = v.u + 0x7fff + ((v.u >> 16) & 1);   // RNE
  return (unsigned short)(r >> 16);
}

static __device__ __forceinline__ float bf2f(unsigned us) {
  union { float f; unsigned u; } v; v.u = us << 16;
  return v.f;
}

static __device__ __forceinline__ f32x4 mfma16(bf16x8 a, bf16x8 b, f32x4 c) {
  return __builtin_amdgcn_mfma_f32_16x16x32_bf16(a, b, c, 0, 0, 0);
}

// ---------------- K0: prep — W*lnw -> bf16, outW -> bf16, fold dtW@xW[:6] ----------------
__global__ void k_prep(const float* __restrict__ inW, const float* __restrict__ outW,
                       const float* __restrict__ xW, const float* __restrict__ dtW,
                       const float* __restrict__ lnw,
                       unsigned short* __restrict__ inWb, unsigned short* __restrict__ outWb,
                       float* __restrict__ M1t, float* __restrict__ xBC) {
  int i = blockIdx.x * 256 + threadIdx.x;
  if (i < DIN*CH)  inWb[i]  = f2bf(inW[i] * lnw[i & (CH-1)]);   // fold lnw into W cols
  if (i < CH*DIN)  outWb[i] = f2bf(outW[i]);
  if (i < DIN*DIN) {                 // M1t[c*96+d] = sum_r dtW[d,r]*xW[r,c]
    int c = i / DIN, d = i - c*DIN;
    float s = 0.f;
    #pragma unroll
    for (int r = 0; r < RNK; ++r) s += dtW[d*RNK + r] * xW[r*DIN + c];
    M1t[i] = s;
  }
  if (i < DIN*32) {                  // xBC[c*32+n] = xW[6+n, c]  (transposed B/C proj)
    int c = i / 32, n = i - c*32;
    xBC[i] = xW[(RNK + n)*DIN + c];
  }
}

// ---------------- K0b: pvec[d] = sum_c lnw[c]*W[d,c], qvec[d] = sum_c lnb[c]*W[d,c] ----------------
__launch_bounds__(256)
__global__ void k_prep2(const float* __restrict__ inW, const float* __restrict__ lnw,
                        const float* __restrict__ lnb,
                        float* __restrict__ pvec, float* __restrict__ qvec) {
  __shared__ float sp_[4], sq_[4];
  const int d = blockIdx.x;
  const int tid = threadIdx.x;
  const float4* w4 = (const float4*)(inW + (size_t)d*CH);
  const float4* a4 = (const float4*)lnw;
  const float4* b4 = (const float4*)lnb;
  float sp = 0.f, sq = 0.f;
  for (int j = tid; j < CH/4; j += 256) {
    float4 w = w4[j], a = a4[j], b = b4[j];
    sp += w.x*a.x + w.y*a.y + w.z*a.z + w.w*a.w;
    sq += w.x*b.x + w.y*b.y + w.z*b.z + w.w*b.w;
  }
  #pragma unroll
  for (int off = 32; off; off >>= 1) { sp += __shfl_xor(sp, off); sq += __shfl_xor(sq, off); }
  if ((tid & 63) == 0) { sp_[tid>>6] = sp; sq_[tid>>6] = sq; }
  __syncthreads();
  if (tid == 0) {
    pvec[d] = sp_[0] + sp_[1] + sp_[2] + sp_[3];
    qvec[d] = sq_[0] + sq_[1] + sq_[2] + sq_[3];
  }
}

// ---------------- K2: fused LN + in_proj — 512 thr, column-split waves, nt feat loads ----------------
#define K2_KC 128
#define K2_WLD 136   // 272B row stride = 17 x 16B granules (1 mod 8 -> 2-way max = free)

__launch_bounds__(512)
__global__ void k_ln_inproj(const float* __restrict__ feat,
                            const unsigned short* __restrict__ Wb,
                            const float* __restrict__ pvec, const float* __restrict__ qvec,
                            float* __restrict__ xin) {
  __shared__ unsigned short W_lds[DIN][K2_WLD];

  const int tid  = threadIdx.x;
  const int lane = tid & 63;
  const int w    = tid >> 6;      // 0..7
  const int wh   = w & 3;         // row group
  const int wc   = w >> 2;        // col half (0: cols 0-47, 1: cols 48-95)
  const int r    = lane & 15;
  const int g    = lane >> 4;     // k-quadrant
  const int row  = blockIdx.x * 64 + wh*16 + r;

  const float* arow = feat + (size_t)row * CH;

  f32x4 acc[3];
  #pragma unroll
  for (int i = 0; i < 3; ++i) acc[i] = (f32x4){0.f, 0.f, 0.f, 0.f};
  float s = 0.f, q = 0.f;

  for (int kc = 0; kc < CH; kc += K2_KC) {
    __syncthreads();
    // stage W chunk: 96 rows x 128 k (bf16) = 1536 granules = 3 x 512
    #pragma unroll
    for (int i = 0; i < 3; ++i) {
      int j = tid + 512*i;
      int wr = j >> 4, c16 = j & 15;
      *(uint4*)&W_lds[wr][c16*8] = *(const uint4*)(Wb + (size_t)wr*CH + kc + c16*8);
    }
    __syncthreads();
    #pragma unroll
    for (int t = 0; t < 4; ++t) {
      const f32x4* ap = (const f32x4*)(arow + kc + t*32 + g*8);
      f32x4 v0 = __builtin_nontemporal_load(ap);       // feat: streamed once, keep out of L2
      f32x4 v1 = __builtin_nontemporal_load(ap + 1);
      s += v0[0] + v0[1] + v0[2] + v0[3] + v1[0] + v1[1] + v1[2] + v1[3];
      #pragma unroll
      for (int k = 0; k < 4; ++k) { q = fmaf(v0[k], v0[k], q); q = fmaf(v1[k], v1[k], q); }
      union { bf16x8 v; unsigned short u[8]; } af;
      #pragma unroll
      for (int k = 0; k < 4; ++k) { af.u[k] = f2bf(v0[k]); af.u[4+k] = f2bf(v1[k]); }
      const int krd = t*32 + g*8;
      #pragma unroll
      for (int ct = 0; ct < 3; ++ct) {
        bf16x8 wf = *(const bf16x8*)&W_lds[wc*48 + ct*16 + r][krd];
        acc[ct] = mfma16(wf, af.v, acc[ct]);   // M-dim = W cols, N-dim = feat rows
      }
    }
  }

  // finish row stats: lanes {r, r+16, r+32, r+48} cover disjoint k-subsets of row r
  s += __shfl_xor(s, 16); s += __shfl_xor(s, 32);
  q += __shfl_xor(q, 16); q += __shfl_xor(q, 32);
  const float mu = s * (1.f/CH);
  const float rs = rsqrtf(q*(1.f/CH) - mu*mu + 1e-5f);

  // epilogue: lane holds row, cols wc*48 + ct*16 + g*4 + {0..3} -> float4 stores
  float* orow = xin + (size_t)row * DIN;
  #pragma unroll
  for (int ct = 0; ct < 3; ++ct) {
    const int col = wc*48 + ct*16 + g*4;
    float4 pv = *(const float4*)(pvec + col);
    float4 qv = *(const float4*)(qvec + col);
    f32x4 a = acc[ct];
    float4 o;
    o.x = rs*a[0] - rs*mu*pv.x + qv.x;
    o.y = rs*a[1] - rs*mu*pv.y + qv.y;
    o.z = rs*a[2] - rs*mu*pv.z + qv.z;
    o.w = rs*a[3] - rs*mu*pv.w + qv.w;
    *(float4*)(orow + col) = o;
  }
}

// ---------------- K3: depthwise conv3 + silu + x_proj/dt_proj ----------------
// duT written TRANSPOSED [b][d][t] as packed bf16 pairs {dl, u} (lo=dl, hi=u).
#define K3_R 8
__launch_bounds__(128)
__global__ void k_conv_proj(const float* __restrict__ xin,
                            const float* __restrict__ cw, const float* __restrict__ cb,
                            const float* __restrict__ xBC, const float* __restrict__ M1t,
                            const float* __restrict__ dtb,
                            unsigned* __restrict__ duT,
                            float* __restrict__ Bg, float* __restrict__ Cg) {
  __shared__ float su[K3_R][DIN];
  const int b  = blockIdx.y;
  const int l0 = blockIdx.x * K3_R;
  const int t  = threadIdx.x;

  float ua[K3_R];
  if (t < DIN) {
    float x[K3_R + 2];
    #pragma unroll
    for (int i = 0; i < K3_R + 2; ++i) {
      int li = l0 - 1 + i;
      x[i] = (li >= 0 && li < LEN) ? xin[((size_t)b*LEN + li)*DIN + t] : 0.f;
    }
    float w0 = cw[t*3], w1 = cw[t*3+1], w2 = cw[t*3+2], bb = cb[t];
    #pragma unroll
    for (int r = 0; r < K3_R; ++r) {
      float c = w0*x[r] + w1*x[r+1] + w2*x[r+2] + bb;
      float uu = c / (1.f + __expf(-c));        // silu
      su[r][t] = uu;
      ua[r] = uu;
    }
  }
  __syncthreads();
  if (t < DIN) {
    float z[K3_R];
    #pragma unroll
    for (int r = 0; r < K3_R; ++r) z[r] = dtb[t];
    for (int c = 0; c < DIN; ++c) {
      float m = M1t[c*DIN + t];                 // coalesced
      #pragma unroll
      for (int r = 0; r < K3_R; ++r) z[r] += su[r][c] * m;
    }
    unsigned du[K3_R];
    #pragma unroll
    for (int r = 0; r < K3_R; ++r) {
      float zz = z[r];
      float sp = (zz > 20.f) ? zz : log1pf(__expf(zz));
      float da = 0.001f * sp;
      du[r] = (unsigned)f2bf(da) | ((unsigned)f2bf(ua[r]) << 16);
    }
    unsigned* dp = duT + ((size_t)(b*DIN + t))*LEN + l0;
    *(uint4*)(dp)     = make_uint4(du[0], du[1], du[2], du[3]);
    *(uint4*)(dp + 4) = make_uint4(du[4], du[5], du[6], du[7]);
  } else if (t < DIN + 32) {
    int n = t - DIN;
    float s[K3_R];
    #pragma unroll
    for (int r = 0; r < K3_R; ++r) s[r] = 0.f;
    for (int c = 0; c < DIN; ++c) {
      float wv = xBC[c*32 + n];                 // coalesced
      #pragma unroll
      for (int r = 0; r < K3_R; ++r) s[r] += su[r][c] * wv;
    }
    #pragma unroll
    for (int r = 0; r < K3_R; ++r) {
      size_t row = (size_t)b*LEN + l0 + r;
      if (n < 16) Bg[row*NST + n]        = s[r];
      else        Cg[row*NST + (n - 16)] = s[r];
    }
  }
}

// ---------------- K4a: chunked scan pass 1 — 4 states/lane, packed duT loads ----------------
// lane quad (nq=tid&3) holds n = nq*4..+3 of pair (tid>>2); 64 pairs/block; grid (24, 32)
__launch_bounds__(256)
__global__ void k_scan1(const unsigned* __restrict__ duT,
                        const float* __restrict__ Bg, const float* __restrict__ Alog,
                        float* __restrict__ carryS, float* __restrict__ carryD) {
  const int tid  = threadIdx.x;
  const int nq   = tid & 3;
  const int pair = blockIdx.x * 64 + (tid >> 2);
  const int chunk = blockIdx.y;
  const int b = pair / DIN, d = pair - b*DIN;
  f32x4 Al = *(const f32x4*)(Alog + d*NST + nq*4);
  f32x4 An4;
  #pragma unroll
  for (int k = 0; k < 4; ++k) An4[k] = -__expf(Al[k]);
  const unsigned* dup = duT + ((size_t)(b*DIN + d))*LEN + chunk*TCH;
  const float* bp_ = Bg + ((size_t)b*LEN + chunk*TCH)*NST + nq*4;

  f32x4 s4 = (f32x4){0.f, 0.f, 0.f, 0.f};
  float sdl = 0.f;
  #pragma unroll 2
  for (int tq = 0; tq < TCH/4; ++tq) {
    u32x4 du4 = *(const u32x4*)(dup + tq*4);
    #pragma unroll
    for (int j = 0; j < 4; ++j) {
      unsigned pk = du4[j];
      float dl = bf2f(pk & 0xffffu);
      float uu = bf2f(pk >> 16);
      f32x4 bp4 = *(const f32x4*)(bp_ + (size_t)(tq*4 + j)*NST);
      f32x4 dA;
      #pragma unroll
      for (int k = 0; k < 4; ++k) dA[k] = __expf(dl*An4[k]);
      float du = dl * uu;
      s4 = dA*s4 + du*bp4;
      sdl += dl;
    }
  }
  *(f32x4*)(carryS + (size_t)(pair*NCHK + chunk)*16 + nq*4) = s4;
  if (nq == 0) carryD[pair*NCHK + chunk] = sdl;
}

// ---------------- K4c: chunked scan pass 2 — inline carry combine + recompute + y ----------------
__launch_bounds__(256)
__global__ void k_scan3(const unsigned* __restrict__ duT,
                        const float* __restrict__ Bg, const float* __restrict__ Cg,
                        const float* __restrict__ Alog, const float* __restrict__ Dp,
                        const float* __restrict__ carryS, const float* __restrict__ carryD,
                        unsigned short* __restrict__ yb) {
  const int tid  = threadIdx.x;
  const int nq   = tid & 3;
  const int pair = blockIdx.x * 64 + (tid >> 2);
  const int chunk = blockIdx.y;
  const int b = pair / DIN, d = pair - b*DIN;
  f32x4 Al = *(const f32x4*)(Alog + d*NST + nq*4);
  f32x4 An4;
  #pragma unroll
  for (int k = 0; k < 4; ++k) An4[k] = -__expf(Al[k]);
  const float Dd = Dp[d];

  // inline scan2: combine carries of chunks < mine (L2-hot; <=31 iterations)
  f32x4 s4 = (f32x4){0.f, 0.f, 0.f, 0.f};
  for (int c = 0; c < chunk; ++c) {
    float cd = carryD[pair*NCHK + c];
    f32x4 cs = *(const f32x4*)(carryS + (size_t)(pair*NCHK + c)*16 + nq*4);
    f32x4 dA;
    #pragma unroll
    for (int k = 0; k < 4; ++k) dA[k] = __expf(An4[k] * cd);
    s4 = dA*s4 + cs;
  }

  const unsigned* dup = duT + ((size_t)(b*DIN + d))*LEN + chunk*TCH;
  const float* bp_ = Bg + ((size_t)b*LEN + chunk*TCH)*NST + nq*4;
  const float* cp_ = Cg + ((size_t)b*LEN + chunk*TCH)*NST + nq*4;
  unsigned short* yp = yb + ((size_t)b*LEN + chunk*TCH)*DIN + d;

  #pragma unroll 2
  for (int tq = 0; tq < TCH/4; ++tq) {
    u32x4 du4 = *(const u32x4*)(dup + tq*4);
    #pragma unroll
    for (int j = 0; j < 4; ++j) {
      unsigned pk = du4[j];
      float dl = bf2f(pk & 0xffffu);
      float uu = bf2f(pk >> 16);
      f32x4 bp4 = *(const f32x4*)(bp_ + (size_t)(tq*4 + j)*NST);
      f32x4 cp4 = *(const f32x4*)(cp_ + (size_t)(tq*4 + j)*NST);
      f32x4 dA;
      #pragma unroll
      for (int k = 0; k < 4; ++k) dA[k] = __expf(dl*An4[k]);
      float du = dl * uu;
      s4 = dA*s4 + du*bp4;
      f32x4 pv = s4 * cp4;
      float py = (pv[0] + pv[1]) + (pv[2] + pv[3]);
      py += __shfl_xor(py, 1);
      py += __shfl_xor(py, 2);
      if (nq == 0) yp[(size_t)(tq*4 + j)*DIN] = f2bf(py + uu*Dd);
    }
  }
}

// ---------------- K5: out_proj (bf16 MFMA) + residual — 512 thr, nt load/store epilogue ----------------
#define K6_MR 128
#define K6_NC 128
#define K6_LD 104   // 208B row stride = 13 x 16B granules (5 mod 8 -> 2-way max = free)

__launch_bounds__(512)
__global__ void k_outproj(const unsigned short* __restrict__ yb,
                          const unsigned short* __restrict__ Wb,  // (2048 x 96) bf16
                          const float* __restrict__ resid,
                          float* __restrict__ out) {
  __shared__ unsigned short W_lds[K6_NC][K6_LD];
  const int tid  = threadIdx.x;
  const int lane = tid & 63;
  const int w    = tid >> 6;      // 0..7: wave's 16-row group
  const int r    = lane & 15;
  const int g    = lane >> 4;
  const int r0   = blockIdx.y * K6_MR;
  const int c0   = blockIdx.x * K6_NC;

  // stage W tile: 128 rows x 96 k = 12 granules/row = 1536 items = 3 x 512
  #pragma unroll
  for (int i = 0; i < 3; ++i) {
    int j = tid + 512*i;
    int row = j / 12, c8 = j - row*12;
    *(uint4*)&W_lds[row][c8*8] = *(const uint4*)(Wb + (size_t)(c0 + row)*DIN + c8*8);
  }
  __syncthreads();

  f32x4 acc[8];
  #pragma unroll
  for (int i = 0; i < 8; ++i) acc[i] = (f32x4){0.f, 0.f, 0.f, 0.f};

  const unsigned short* yrow = yb + (size_t)(r0 + w*16 + r)*DIN;
  #pragma unroll
  for (int kt = 0; kt < 3; ++kt) {     // K = 96 = 3 x 32
    const int krd = kt*32 + g*8;
    bf16x8 y0 = *(const bf16x8*)(yrow + krd);
    #pragma unroll
    for (int ci = 0; ci < 8; ++ci) {
      bf16x8 wf = *(const bf16x8*)&W_lds[ci*16 + r][krd];
      acc[ci] = mfma16(wf, y0, acc[ci]);   // M-dim = out cols, N-dim = out rows
    }
  }

  // epilogue: lane -> row (w*16 + r), cols ci*16 + g*4 + {0..3}: nt f32x4 RMW
  const size_t row = (size_t)(r0 + w*16 + r);
  #pragma unroll
  for (int ci = 0; ci < 8; ++ci) {
    size_t col = (size_t)(c0 + ci*16 + g*4);
    const f32x4 rv = __builtin_nontemporal_load((const f32x4*)(resid + row*CH + col));
    f32x4 o = acc[ci] + rv;
    __builtin_nontemporal_store(o, (f32x4*)(out + row*CH + col));  // out never re-read
  }
}

extern "C" void kernel_launch(void* const* d_in, const int* in_sizes, int n_in,
                              void* d_out, int out_size, void* d_ws, size_t ws_size,
                              hipStream_t stream) {
  const float* feat = (const float*)d_in[0];
  const float* lnw  = (const float*)d_in[1];
  const float* lnb  = (const float*)d_in[2];
  const float* inW  = (const float*)d_in[3];
  const float* cw   = (const float*)d_in[4];
  const float* cb   = (const float*)d_in[5];
  const float* xW   = (const float*)d_in[6];
  const float* dtW  = (const float*)d_in[7];
  const float* dtb  = (const float*)d_in[8];
  const float* Alog = (const float*)d_in[9];
  const float* Dp   = (const float*)d_in[10];
  const float* outW = (const float*)d_in[11];
  float* out = (float*)d_out;

  char* ws = (char*)d_ws;
  size_t off = 0;
  auto alloc = [&](size_t bytes) { void* p = ws + off; off += (bytes + 255) & ~255ull; return p; };
  unsigned short* inWb  = (unsigned short*)alloc((size_t)DIN*CH*2);
  unsigned short* outWb = (unsigned short*)alloc((size_t)CH*DIN*2);
  float* M1t = (float*)alloc((size_t)DIN*DIN*4);
  float* xBC = (float*)alloc((size_t)DIN*32*4);
  float* pvec = (float*)alloc((size_t)DIN*4);
  float* qvec = (float*)alloc((size_t)DIN*4);
  float* xin = (float*)alloc((size_t)NROW*DIN*4);
  unsigned* duT = (unsigned*)alloc((size_t)NROW*DIN*4);   // packed {dl,u} bf16 pairs
  float* Bg  = (float*)alloc((size_t)NROW*NST*4);
  float* Cg  = (float*)alloc((size_t)NROW*NST*4);
  unsigned short* yb = (unsigned short*)alloc((size_t)NROW*DIN*2);
  float* carryS = (float*)alloc((size_t)NPAIR*NCHK*NST*4);
  float* carryD = (float*)alloc((size_t)NPAIR*NCHK*4);

  hipLaunchKernelGGL(k_prep, dim3((DIN*CH + 255)/256), dim3(256), 0, stream,
                     inW, outW, xW, dtW, lnw, inWb, outWb, M1t, xBC);
  hipLaunchKernelGGL(k_prep2, dim3(DIN), dim3(256), 0, stream,
                     inW, lnw, lnb, pvec, qvec);
  hipLaunchKernelGGL(k_ln_inproj, dim3(NROW/64), dim3(512), 0, stream,
                     feat, inWb, pvec, qvec, xin);
  hipLaunchKernelGGL(k_conv_proj, dim3(LEN/K3_R, BSZ), dim3(128), 0, stream,
                     xin, cw, cb, xBC, M1t, dtb, duT, Bg, Cg);
  hipLaunchKernelGGL(k_scan1, dim3(NPAIR/64, NCHK), dim3(256), 0, stream,
                     duT, Bg, Alog, carryS, carryD);
  hipLaunchKernelGGL(k_scan3, dim3(NPAIR/64, NCHK), dim3(256), 0, stream,
                     duT, Bg, Cg, Alog, Dp, carryS, carryD, yb);
  hipLaunchKernelGGL(k_outproj, dim3(CH/K6_NC, NROW/K6_MR), dim3(512), 0, stream,
                     yb, outWb, feat, out);
}

// Round 14
// 342.724 us; speedup vs baseline: 1.6295x; 1.0104x over previous
//
#include <hip/hip_runtime.h>
#include <hip/hip_bf16.h>

#define BSZ 16
#define LEN 2048
#define CH  2048
#define DIN 96
#define NST 16
#define RNK 6
#define NROW (BSZ*LEN)   // 32768
#define TCH  64
#define NCHK (LEN/TCH)   // 32
#define NPAIR (BSZ*DIN)  // 1536

typedef __attribute__((ext_vector_type(4))) float f32x4;
typedef __attribute__((ext_vector_type(4))) unsigned u32x4;
typedef __attribute__((ext_vector_type(8))) short bf16x8;

static __device__ __forceinline__ unsigned short f2bf(float f) {
  union { float f; unsigned u; } v; v.f = f;
  unsigned r = v.u + 0x7fff + ((v.u >> 16) & 1);   // RNE
  return (unsigned short)(r >> 16);
}

static __device__ __forceinline__ float bf2f(unsigned us) {
  union { float f; unsigned u; } v; v.u = us << 16;
  return v.f;
}

static __device__ __forceinline__ f32x4 mfma16(bf16x8 a, bf16x8 b, f32x4 c) {
  return __builtin_amdgcn_mfma_f32_16x16x32_bf16(a, b, c, 0, 0, 0);
}

// ---------------- K0: prep (merged) — weights->bf16, fold dtW@xW[:6] -> M1[d][c],
//                  xBCt[n][c], and pvec/qvec reduction (blocks 768..863) ----------------
__launch_bounds__(256)
__global__ void k_prep(const float* __restrict__ inW, const float* __restrict__ outW,
                       const float* __restrict__ xW, const float* __restrict__ dtW,
                       const float* __restrict__ lnw, const float* __restrict__ lnb,
                       unsigned short* __restrict__ inWb, unsigned short* __restrict__ outWb,
                       float* __restrict__ M1, float* __restrict__ xBCt,
                       float* __restrict__ pvec, float* __restrict__ qvec) {
  const int bid = blockIdx.x;
  const int tid = threadIdx.x;
  if (bid < 768) {
    int i = bid * 256 + tid;
    if (i < DIN*CH)  inWb[i]  = f2bf(inW[i] * lnw[i & (CH-1)]);   // fold lnw into W cols
    if (i < CH*DIN)  outWb[i] = f2bf(outW[i]);
    if (i < DIN*DIN) {               // M1[d*96+c] = sum_r dtW[d,r]*xW[r,c]
      int d = i / DIN, c = i - d*DIN;
      float s = 0.f;
      #pragma unroll
      for (int r = 0; r < RNK; ++r) s += dtW[d*RNK + r] * xW[r*DIN + c];
      M1[i] = s;
    }
    if (i < 32*DIN) xBCt[i] = xW[RNK*DIN + i];   // xBCt[n*96+c] = xW[6+n, c]
  } else {
    // pvec[d] = sum_c lnw[c]*W[d,c]; qvec[d] = sum_c lnb[c]*W[d,c]
    __shared__ float sp_[4], sq_[4];
    const int d = bid - 768;
    const float4* w4 = (const float4*)(inW + (size_t)d*CH);
    const float4* a4 = (const float4*)lnw;
    const float4* b4 = (const float4*)lnb;
    float sp = 0.f, sq = 0.f;
    for (int j = tid; j < CH/4; j += 256) {
      float4 w = w4[j], a = a4[j], b = b4[j];
      sp += w.x*a.x + w.y*a.y + w.z*a.z + w.w*a.w;
      sq += w.x*b.x + w.y*b.y + w.z*b.z + w.w*b.w;
    }
    #pragma unroll
    for (int off = 32; off; off >>= 1) { sp += __shfl_xor(sp, off); sq += __shfl_xor(sq, off); }
    if ((tid & 63) == 0) { sp_[tid>>6] = sp; sq_[tid>>6] = sq; }
    __syncthreads();
    if (tid == 0) {
      pvec[d] = sp_[0] + sp_[1] + sp_[2] + sp_[3];
      qvec[d] = sq_[0] + sq_[1] + sq_[2] + sq_[3];
    }
  }
}

// ---------------- K2: fused LN + in_proj — 512 thr, column-split waves, nt feat loads ----------------
#define K2_KC 128
#define K2_WLD 136   // 272B row stride = 17 x 16B granules (1 mod 8 -> 2-way max = free)

__launch_bounds__(512)
__global__ void k_ln_inproj(const float* __restrict__ feat,
                            const unsigned short* __restrict__ Wb,
                            const float* __restrict__ pvec, const float* __restrict__ qvec,
                            float* __restrict__ xin) {
  __shared__ unsigned short W_lds[DIN][K2_WLD];

  const int tid  = threadIdx.x;
  const int lane = tid & 63;
  const int w    = tid >> 6;      // 0..7
  const int wh   = w & 3;         // row group
  const int wc   = w >> 2;        // col half (0: cols 0-47, 1: cols 48-95)
  const int r    = lane & 15;
  const int g    = lane >> 4;     // k-quadrant
  const int row  = blockIdx.x * 64 + wh*16 + r;

  const float* arow = feat + (size_t)row * CH;

  f32x4 acc[3];
  #pragma unroll
  for (int i = 0; i < 3; ++i) acc[i] = (f32x4){0.f, 0.f, 0.f, 0.f};
  float s = 0.f, q = 0.f;

  for (int kc = 0; kc < CH; kc += K2_KC) {
    __syncthreads();
    // stage W chunk: 96 rows x 128 k (bf16) = 1536 granules = 3 x 512
    #pragma unroll
    for (int i = 0; i < 3; ++i) {
      int j = tid + 512*i;
      int wr = j >> 4, c16 = j & 15;
      *(uint4*)&W_lds[wr][c16*8] = *(const uint4*)(Wb + (size_t)wr*CH + kc + c16*8);
    }
    __syncthreads();
    #pragma unroll
    for (int t = 0; t < 4; ++t) {
      const f32x4* ap = (const f32x4*)(arow + kc + t*32 + g*8);
      f32x4 v0 = __builtin_nontemporal_load(ap);       // feat: streamed once, keep out of L2
      f32x4 v1 = __builtin_nontemporal_load(ap + 1);
      s += v0[0] + v0[1] + v0[2] + v0[3] + v1[0] + v1[1] + v1[2] + v1[3];
      #pragma unroll
      for (int k = 0; k < 4; ++k) { q = fmaf(v0[k], v0[k], q); q = fmaf(v1[k], v1[k], q); }
      union { bf16x8 v; unsigned short u[8]; } af;
      #pragma unroll
      for (int k = 0; k < 4; ++k) { af.u[k] = f2bf(v0[k]); af.u[4+k] = f2bf(v1[k]); }
      const int krd = t*32 + g*8;
      #pragma unroll
      for (int ct = 0; ct < 3; ++ct) {
        bf16x8 wf = *(const bf16x8*)&W_lds[wc*48 + ct*16 + r][krd];
        acc[ct] = mfma16(wf, af.v, acc[ct]);   // M-dim = W cols, N-dim = feat rows
      }
    }
  }

  // finish row stats: lanes {r, r+16, r+32, r+48} cover disjoint k-subsets of row r
  s += __shfl_xor(s, 16); s += __shfl_xor(s, 32);
  q += __shfl_xor(q, 16); q += __shfl_xor(q, 32);
  const float mu = s * (1.f/CH);
  const float rs = rsqrtf(q*(1.f/CH) - mu*mu + 1e-5f);

  // epilogue: lane holds row, cols wc*48 + ct*16 + g*4 + {0..3} -> float4 stores
  float* orow = xin + (size_t)row * DIN;
  #pragma unroll
  for (int ct = 0; ct < 3; ++ct) {
    const int col = wc*48 + ct*16 + g*4;
    float4 pv = *(const float4*)(pvec + col);
    float4 qv = *(const float4*)(qvec + col);
    f32x4 a = acc[ct];
    float4 o;
    o.x = rs*a[0] - rs*mu*pv.x + qv.x;
    o.y = rs*a[1] - rs*mu*pv.y + qv.y;
    o.z = rs*a[2] - rs*mu*pv.z + qv.z;
    o.w = rs*a[3] - rs*mu*pv.w + qv.w;
    *(float4*)(orow + col) = o;
  }
}

// ---------------- K3: depthwise conv3 + silu + x_proj/dt_proj (vectorized) ----------------
// duT TRANSPOSED [b][d][t] packed bf16 {dl,u}; bcT [row][n] packed bf16 {B,C}.
#define K3_R 8
__launch_bounds__(128)
__global__ void k_conv_proj(const float* __restrict__ xin,
                            const float* __restrict__ cw, const float* __restrict__ cb,
                            const float* __restrict__ xBCt, const float* __restrict__ M1,
                            const float* __restrict__ dtb,
                            unsigned* __restrict__ duT, unsigned* __restrict__ bcT) {
  __shared__ float su[K3_R][DIN];
  const int b  = blockIdx.y;
  const int l0 = blockIdx.x * K3_R;
  const int t  = threadIdx.x;

  float ua[K3_R];
  if (t < DIN) {
    float x[K3_R + 2];
    #pragma unroll
    for (int i = 0; i < K3_R + 2; ++i) {
      int li = l0 - 1 + i;
      x[i] = (li >= 0 && li < LEN) ? xin[((size_t)b*LEN + li)*DIN + t] : 0.f;
    }
    float w0 = cw[t*3], w1 = cw[t*3+1], w2 = cw[t*3+2], bb = cb[t];
    #pragma unroll
    for (int r = 0; r < K3_R; ++r) {
      float c = w0*x[r] + w1*x[r+1] + w2*x[r+2] + bb;
      float uu = c / (1.f + __expf(-c));        // silu
      su[r][t] = uu;
      ua[r] = uu;
    }
  }
  __syncthreads();
  if (t < DIN) {
    float z[K3_R];
    #pragma unroll
    for (int r = 0; r < K3_R; ++r) z[r] = dtb[t];
    const f32x4* m4 = (const f32x4*)(M1 + t*DIN);
    for (int cq = 0; cq < DIN/4; ++cq) {
      f32x4 m = m4[cq];
      #pragma unroll
      for (int r = 0; r < K3_R; ++r)
        z[r] += su[r][cq*4]*m[0] + su[r][cq*4+1]*m[1] + su[r][cq*4+2]*m[2] + su[r][cq*4+3]*m[3];
    }
    unsigned du[K3_R];
    #pragma unroll
    for (int r = 0; r < K3_R; ++r) {
      float zz = z[r];
      float sp = (zz > 20.f) ? zz : log1pf(__expf(zz));
      float da = 0.001f * sp;
      du[r] = (unsigned)f2bf(da) | ((unsigned)f2bf(ua[r]) << 16);
    }
    unsigned* dp = duT + ((size_t)(b*DIN + t))*LEN + l0;
    *(uint4*)(dp)     = make_uint4(du[0], du[1], du[2], du[3]);
    *(uint4*)(dp + 4) = make_uint4(du[4], du[5], du[6], du[7]);
  } else if (t < DIN + 16) {
    int n = t - DIN;                    // thread computes BOTH B_n and C_n
    float sb[K3_R], sc[K3_R];
    #pragma unroll
    for (int r = 0; r < K3_R; ++r) { sb[r] = 0.f; sc[r] = 0.f; }
    const f32x4* wb4 = (const f32x4*)(xBCt + (size_t)n*DIN);
    const f32x4* wc4 = (const f32x4*)(xBCt + (size_t)(n + 16)*DIN);
    for (int cq = 0; cq < DIN/4; ++cq) {
      f32x4 wb = wb4[cq], wc = wc4[cq];
      #pragma unroll
      for (int r = 0; r < K3_R; ++r) {
        float s0 = su[r][cq*4], s1 = su[r][cq*4+1], s2 = su[r][cq*4+2], s3 = su[r][cq*4+3];
        sb[r] += s0*wb[0] + s1*wb[1] + s2*wb[2] + s3*wb[3];
        sc[r] += s0*wc[0] + s1*wc[1] + s2*wc[2] + s3*wc[3];
      }
    }
    #pragma unroll
    for (int r = 0; r < K3_R; ++r) {
      size_t row = (size_t)b*LEN + l0 + r;
      bcT[row*NST + n] = (unsigned)f2bf(sb[r]) | ((unsigned)f2bf(sc[r]) << 16);
    }
  }
}

// ---------------- K4a: chunked scan pass 1 — 4 states/lane, packed duT/bcT loads ----------------
// lane quad (nq=tid&3) holds n = nq*4..+3 of pair (tid>>2); 64 pairs/block; grid (24, 32)
__launch_bounds__(256)
__global__ void k_scan1(const unsigned* __restrict__ duT, const unsigned* __restrict__ bcT,
                        const float* __restrict__ Alog,
                        float* __restrict__ carryS, float* __restrict__ carryD) {
  const int tid  = threadIdx.x;
  const int nq   = tid & 3;
  const int pair = blockIdx.x * 64 + (tid >> 2);
  const int chunk = blockIdx.y;
  const int b = pair / DIN, d = pair - b*DIN;
  f32x4 Al = *(const f32x4*)(Alog + d*NST + nq*4);
  f32x4 An4;
  #pragma unroll
  for (int k = 0; k < 4; ++k) An4[k] = -__expf(Al[k]);
  const unsigned* dup = duT + ((size_t)(b*DIN + d))*LEN + chunk*TCH;
  const unsigned* bcp = bcT + ((size_t)b*LEN + chunk*TCH)*NST + nq*4;

  f32x4 s4 = (f32x4){0.f, 0.f, 0.f, 0.f};
  float sdl = 0.f;
  #pragma unroll 2
  for (int tq = 0; tq < TCH/4; ++tq) {
    u32x4 du4 = *(const u32x4*)(dup + tq*4);
    #pragma unroll
    for (int j = 0; j < 4; ++j) {
      unsigned pk = du4[j];
      float dl = bf2f(pk & 0xffffu);
      float uu = bf2f(pk >> 16);
      u32x4 bc4 = *(const u32x4*)(bcp + (size_t)(tq*4 + j)*NST);
      f32x4 bp4, dA;
      #pragma unroll
      for (int k = 0; k < 4; ++k) { bp4[k] = bf2f(bc4[k] & 0xffffu); dA[k] = __expf(dl*An4[k]); }
      float du = dl * uu;
      s4 = dA*s4 + du*bp4;
      sdl += dl;
    }
  }
  *(f32x4*)(carryS + (size_t)(pair*NCHK + chunk)*16 + nq*4) = s4;
  if (nq == 0) carryD[pair*NCHK + chunk] = sdl;
}

// ---------------- K4c: chunked scan pass 2 — inline carry combine + recompute + y ----------------
__launch_bounds__(256)
__global__ void k_scan3(const unsigned* __restrict__ duT, const unsigned* __restrict__ bcT,
                        const float* __restrict__ Alog, const float* __restrict__ Dp,
                        const float* __restrict__ carryS, const float* __restrict__ carryD,
                        unsigned short* __restrict__ yb) {
  const int tid  = threadIdx.x;
  const int nq   = tid & 3;
  const int pair = blockIdx.x * 64 + (tid >> 2);
  const int chunk = blockIdx.y;
  const int b = pair / DIN, d = pair - b*DIN;
  f32x4 Al = *(const f32x4*)(Alog + d*NST + nq*4);
  f32x4 An4;
  #pragma unroll
  for (int k = 0; k < 4; ++k) An4[k] = -__expf(Al[k]);
  const float Dd = Dp[d];

  // inline scan2: combine carries of chunks < mine (L2-hot; <=31 iterations)
  f32x4 s4 = (f32x4){0.f, 0.f, 0.f, 0.f};
  for (int c = 0; c < chunk; ++c) {
    float cd = carryD[pair*NCHK + c];
    f32x4 cs = *(const f32x4*)(carryS + (size_t)(pair*NCHK + c)*16 + nq*4);
    f32x4 dA;
    #pragma unroll
    for (int k = 0; k < 4; ++k) dA[k] = __expf(An4[k] * cd);
    s4 = dA*s4 + cs;
  }

  const unsigned* dup = duT + ((size_t)(b*DIN + d))*LEN + chunk*TCH;
  const unsigned* bcp = bcT + ((size_t)b*LEN + chunk*TCH)*NST + nq*4;
  unsigned short* yp = yb + ((size_t)b*LEN + chunk*TCH)*DIN + d;

  #pragma unroll 2
  for (int tq = 0; tq < TCH/4; ++tq) {
    u32x4 du4 = *(const u32x4*)(dup + tq*4);
    #pragma unroll
    for (int j = 0; j < 4; ++j) {
      unsigned pk = du4[j];
      float dl = bf2f(pk & 0xffffu);
      float uu = bf2f(pk >> 16);
      u32x4 bc4 = *(const u32x4*)(bcp + (size_t)(tq*4 + j)*NST);
      f32x4 bp4, cp4, dA;
      #pragma unroll
      for (int k = 0; k < 4; ++k) {
        bp4[k] = bf2f(bc4[k] & 0xffffu);
        cp4[k] = bf2f(bc4[k] >> 16);
        dA[k]  = __expf(dl*An4[k]);
      }
      float du = dl * uu;
      s4 = dA*s4 + du*bp4;
      f32x4 pv = s4 * cp4;
      float py = (pv[0] + pv[1]) + (pv[2] + pv[3]);
      py += __shfl_xor(py, 1);
      py += __shfl_xor(py, 2);
      if (nq == 0) yp[(size_t)(tq*4 + j)*DIN] = f2bf(py + uu*Dd);
    }
  }
}

// ---------------- K5: out_proj (bf16 MFMA) + residual — 512 thr, nt load/store epilogue ----------------
#define K6_MR 128
#define K6_NC 128
#define K6_LD 104   // 208B row stride = 13 x 16B granules (5 mod 8 -> 2-way max = free)

__launch_bounds__(512)
__global__ void k_outproj(const unsigned short* __restrict__ yb,
                          const unsigned short* __restrict__ Wb,  // (2048 x 96) bf16
                          const float* __restrict__ resid,
                          float* __restrict__ out) {
  __shared__ unsigned short W_lds[K6_NC][K6_LD];
  const int tid  = threadIdx.x;
  const int lane = tid & 63;
  const int w    = tid >> 6;      // 0..7: wave's 16-row group
  const int r    = lane & 15;
  const int g    = lane >> 4;
  const int r0   = blockIdx.y * K6_MR;
  const int c0   = blockIdx.x * K6_NC;

  // stage W tile: 128 rows x 96 k = 12 granules/row = 1536 items = 3 x 512
  #pragma unroll
  for (int i = 0; i < 3; ++i) {
    int j = tid + 512*i;
    int row = j / 12, c8 = j - row*12;
    *(uint4*)&W_lds[row][c8*8] = *(const uint4*)(Wb + (size_t)(c0 + row)*DIN + c8*8);
  }
  __syncthreads();

  f32x4 acc[8];
  #pragma unroll
  for (int i = 0; i < 8; ++i) acc[i] = (f32x4){0.f, 0.f, 0.f, 0.f};

  const unsigned short* yrow = yb + (size_t)(r0 + w*16 + r)*DIN;
  #pragma unroll
  for (int kt = 0; kt < 3; ++kt) {     // K = 96 = 3 x 32
    const int krd = kt*32 + g*8;
    bf16x8 y0 = *(const bf16x8*)(yrow + krd);
    #pragma unroll
    for (int ci = 0; ci < 8; ++ci) {
      bf16x8 wf = *(const bf16x8*)&W_lds[ci*16 + r][krd];
      acc[ci] = mfma16(wf, y0, acc[ci]);   // M-dim = out cols, N-dim = out rows
    }
  }

  // epilogue: lane -> row (w*16 + r), cols ci*16 + g*4 + {0..3}: nt f32x4 RMW
  const size_t row = (size_t)(r0 + w*16 + r);
  #pragma unroll
  for (int ci = 0; ci < 8; ++ci) {
    size_t col = (size_t)(c0 + ci*16 + g*4);
    const f32x4 rv = __builtin_nontemporal_load((const f32x4*)(resid + row*CH + col));
    f32x4 o = acc[ci] + rv;
    __builtin_nontemporal_store(o, (f32x4*)(out + row*CH + col));  // out never re-read
  }
}

extern "C" void kernel_launch(void* const* d_in, const int* in_sizes, int n_in,
                              void* d_out, int out_size, void* d_ws, size_t ws_size,
                              hipStream_t stream) {
  const float* feat = (const float*)d_in[0];
  const float* lnw  = (const float*)d_in[1];
  const float* lnb  = (const float*)d_in[2];
  const float* inW  = (const float*)d_in[3];
  const float* cw   = (const float*)d_in[4];
  const float* cb   = (const float*)d_in[5];
  const float* xW   = (const float*)d_in[6];
  const float* dtW  = (const float*)d_in[7];
  const float* dtb  = (const float*)d_in[8];
  const float* Alog = (const float*)d_in[9];
  const float* Dp   = (const float*)d_in[10];
  const float* outW = (const float*)d_in[11];
  float* out = (float*)d_out;

  char* ws = (char*)d_ws;
  size_t off = 0;
  auto alloc = [&](size_t bytes) { void* p = ws + off; off += (bytes + 255) & ~255ull; return p; };
  unsigned short* inWb  = (unsigned short*)alloc((size_t)DIN*CH*2);
  unsigned short* outWb = (unsigned short*)alloc((size_t)CH*DIN*2);
  float* M1   = (float*)alloc((size_t)DIN*DIN*4);
  float* xBCt = (float*)alloc((size_t)32*DIN*4);
  float* pvec = (float*)alloc((size_t)DIN*4);
  float* qvec = (float*)alloc((size_t)DIN*4);
  float* xin = (float*)alloc((size_t)NROW*DIN*4);
  unsigned* duT = (unsigned*)alloc((size_t)NROW*DIN*4);   // packed {dl,u} bf16 pairs
  unsigned* bcT = (unsigned*)alloc((size_t)NROW*NST*4);   // packed {B,C} bf16 pairs
  unsigned short* yb = (unsigned short*)alloc((size_t)NROW*DIN*2);
  float* carryS = (float*)alloc((size_t)NPAIR*NCHK*NST*4);
  float* carryD = (float*)alloc((size_t)NPAIR*NCHK*4);

  hipLaunchKernelGGL(k_prep, dim3(768 + 96), dim3(256), 0, stream,
                     inW, outW, xW, dtW, lnw, lnb, inWb, outWb, M1, xBCt, pvec, qvec);
  hipLaunchKernelGGL(k_ln_inproj, dim3(NROW/64), dim3(512), 0, stream,
                     feat, inWb, pvec, qvec, xin);
  hipLaunchKernelGGL(k_conv_proj, dim3(LEN/K3_R, BSZ), dim3(128), 0, stream,
                     xin, cw, cb, xBCt, M1, dtb, duT, bcT);
  hipLaunchKernelGGL(k_scan1, dim3(NPAIR/64, NCHK), dim3(256), 0, stream,
                     duT, bcT, Alog, carryS, carryD);
  hipLaunchKernelGGL(k_scan3, dim3(NPAIR/64, NCHK), dim3(256), 0, stream,
                     duT, bcT, Alog, Dp, carryS, carryD, yb);
  hipLaunchKernelGGL(k_outproj, dim3(CH/K6_NC, NROW/K6_MR), dim3(512), 0, stream,
                     yb, outWb, feat, out);
}